// Round 18
// baseline (129.026 us; speedup 1.0000x reference)
//
#include <hip/hip_runtime.h>
#include <hip/hip_fp16.h>

#define LL 16384
#define HH 128
#define WW 128
#define CC 64
#define NH 8
#define EPSF 1e-7f
#define KVCHUNKS 32

typedef __attribute__((ext_vector_type(8))) _Float16 f16x8;
typedef __attribute__((ext_vector_type(4))) float f32x4;
typedef __attribute__((ext_vector_type(8))) unsigned short u16x8;

static __device__ __forceinline__ unsigned short f2h_bits(float v) {
    const _Float16 h = (_Float16)v;
    unsigned short b;
    __builtin_memcpy(&b, &h, 2);
    return b;
}
static __device__ __forceinline__ float h2f(unsigned short b) {
    _Float16 h;
    __builtin_memcpy(&h, &b, 2);
    return (float)h;
}

// ---------------- Kernel A: qkv 1x1 conv + bias (+relu on q,k) via MFMA hi/lo ----------
// q written as single f16 (feeds num/denom ratio in attn -> error largely cancels).
__global__ void qkv_kernel(const float* __restrict__ x, const float* __restrict__ w,
                           const float* __restrict__ bias,
                           unsigned short* __restrict__ q, float* __restrict__ k,
                           float* __restrict__ v) {
    const int pix0 = blockIdx.x * 128;
    const int b    = blockIdx.y;
    const int sec  = blockIdx.z;
    const int tid  = threadIdx.x;
    const int lane = tid & 63;
    const int wv   = tid >> 6;

    __shared__ _Float16 xh[128][72], xl[128][72];
    __shared__ _Float16 wh[64][72],  wl[64][72];

    {
        const float* xb = x + (size_t)b * CC * LL + pix0;
        for (int idx = tid; idx < 64 * 128; idx += 256) {
            const int ci = idx >> 7;
            const int px = idx & 127;
            const float vv = xb[(size_t)ci * LL + px];
            const _Float16 h = (_Float16)vv;
            xh[px][ci] = h;
            xl[px][ci] = (_Float16)(vv - (float)h);
        }
    }
    {
        const float* wsec = w + (size_t)sec * 64 * 64;
        for (int idx = tid; idx < 64 * 64; idx += 256) {
            const int co = idx >> 6;
            const int ci = idx & 63;
            const float vv = wsec[co * 64 + ci];
            const _Float16 h = (_Float16)vv;
            wh[co][ci] = h;
            wl[co][ci] = (_Float16)(vv - (float)h);
        }
    }
    __syncthreads();

    f32x4 acc[4][2];
#pragma unroll
    for (int ct = 0; ct < 4; ++ct)
#pragma unroll
        for (int pt = 0; pt < 2; ++pt) acc[ct][pt] = (f32x4)0.f;

    const int g8 = (lane >> 4) * 8;
    const int rl = lane & 15;

#pragma unroll
    for (int ks = 0; ks < 2; ++ks) {
        const int kb = ks * 32 + g8;
        f16x8 ah[4], al[4], bh[2], bl[2];
#pragma unroll
        for (int ct = 0; ct < 4; ++ct) {
            ah[ct] = *(const f16x8*)&wh[ct * 16 + rl][kb];
            al[ct] = *(const f16x8*)&wl[ct * 16 + rl][kb];
        }
#pragma unroll
        for (int pt = 0; pt < 2; ++pt) {
            bh[pt] = *(const f16x8*)&xh[wv * 32 + pt * 16 + rl][kb];
            bl[pt] = *(const f16x8*)&xl[wv * 32 + pt * 16 + rl][kb];
        }
#pragma unroll
        for (int ct = 0; ct < 4; ++ct)
#pragma unroll
            for (int pt = 0; pt < 2; ++pt) {
                acc[ct][pt] = __builtin_amdgcn_mfma_f32_16x16x32_f16(ah[ct], bh[pt], acc[ct][pt], 0, 0, 0);
                acc[ct][pt] = __builtin_amdgcn_mfma_f32_16x16x32_f16(ah[ct], bl[pt], acc[ct][pt], 0, 0, 0);
                acc[ct][pt] = __builtin_amdgcn_mfma_f32_16x16x32_f16(al[ct], bh[pt], acc[ct][pt], 0, 0, 0);
            }
    }

#pragma unroll
    for (int ct = 0; ct < 4; ++ct) {
        const int co_b = ct * 16 + (lane >> 4) * 4;
#pragma unroll
        for (int pt = 0; pt < 2; ++pt) {
            const int px = pix0 + wv * 32 + pt * 16 + rl;
#pragma unroll
            for (int j = 0; j < 4; ++j) {
                const int co = co_b + j;
                float val = acc[ct][pt][j] + bias[sec * 64 + co];
                if (sec == 0) {
                    val = fmaxf(val, 0.f);
                    q[((size_t)b * 64 + co) * LL + px] = f2h_bits(val);
                } else if (sec == 1) {
                    val = fmaxf(val, 0.f);
                    k[((size_t)b * 64 + co) * LL + px] = val;
                } else {
                    v[((size_t)b * 64 + co) * LL + px] = val;
                }
            }
        }
    }
}

// ---------------- Kernel B: KV/KS partials, K staged in LDS ----------------
__global__ void kv_kernel(const float* __restrict__ k, const float* __restrict__ v,
                          float* __restrict__ KVp) {
    const int chunk = blockIdx.x;
    const int h = blockIdx.y;
    const int b = blockIdx.z;
    const int tid = threadIdx.x;
    const int c  = tid >> 5;
    const int s  = tid & 31;
    const int half = s >> 4;
    const int sl   = s & 15;
    const int cpb  = half * 4;

    __shared__ float klds[8][6][130];

    {
        const float* kb = k + ((size_t)(b * 64) + 8 * h) * LL;
        for (int t = tid; t < 8 * 6 * 130; t += 256) {
            const int ch = t / 780;
            const int r1 = t - ch * 780;
            const int lr = r1 / 130;
            const int cx = r1 - lr * 130;
            const int gy = chunk * 4 + lr - 1;
            const int gx = cx - 1;
            const bool ok = (gy >= 0 && gy < HH && gx >= 0 && gx < WW);
            klds[ch][lr][cx] = ok ? kb[(size_t)ch * LL + gy * WW + gx] : 0.f;
        }
    }
    __syncthreads();

    const float* vb = v + ((size_t)(b * 64) + 8 * h + cpb) * LL;

    float kv4[9][4] = {{0.f}};
    float ks[9] = {0.f};

    for (int r = 0; r < 4; ++r) {
        const int y = chunk * 4 + r;
        for (int g = 0; g < 8; ++g) {
            const int col = g * 16 + sl;
            float vv[4];
#pragma unroll
            for (int cp = 0; cp < 4; ++cp) vv[cp] = vb[(size_t)cp * LL + y * WW + col];
            float k9[9];
#pragma unroll
            for (int dy = 0; dy < 3; ++dy)
#pragma unroll
                for (int dx = 0; dx < 3; ++dx)
                    k9[dy * 3 + dx] = klds[c][r + dy][col + dx];
#pragma unroll
            for (int p = 0; p < 9; ++p) {
                ks[p] += k9[p];
#pragma unroll
                for (int cp = 0; cp < 4; ++cp)
                    kv4[p][cp] = fmaf(k9[p], vv[cp], kv4[p][cp]);
            }
        }
    }

#pragma unroll
    for (int p = 0; p < 9; ++p) {
#pragma unroll
        for (int m = 8; m >= 1; m >>= 1) ks[p] += __shfl_xor(ks[p], m);
#pragma unroll
        for (int cp = 0; cp < 4; ++cp) {
#pragma unroll
            for (int m = 8; m >= 1; m >>= 1) kv4[p][cp] += __shfl_xor(kv4[p][cp], m);
        }
    }

    if (sl == 0) {
        float* dst = KVp + (((size_t)(b * NH + h) * KVCHUNKS) + chunk) * 648;
#pragma unroll
        for (int p = 0; p < 9; ++p) {
#pragma unroll
            for (int cp = 0; cp < 4; ++cp)
                dst[(c * 9 + p) * 8 + cpb + cp] = kv4[p][cp];
            if (half == 0) dst[576 + c * 9 + p] = ks[p];
        }
    }
}

// ---------------- Kernel B2: reduce 32 chunk-partials -> KV, KS ----------------
__global__ void kv_finalize(const float* __restrict__ KVp,
                            float* __restrict__ KV, float* __restrict__ KS) {
    const int bh = blockIdx.x;
    const float* src = KVp + (size_t)bh * KVCHUNKS * 648;
    for (int idx = threadIdx.x; idx < 648; idx += 256) {
        float s0 = 0.f, s1 = 0.f, s2 = 0.f, s3 = 0.f;
#pragma unroll
        for (int ch = 0; ch < KVCHUNKS; ch += 4) {
            s0 += src[(ch + 0) * 648 + idx];
            s1 += src[(ch + 1) * 648 + idx];
            s2 += src[(ch + 2) * 648 + idx];
            s3 += src[(ch + 3) * 648 + idx];
        }
        const float sum = (s0 + s1) + (s2 + s3);
        if (idx < 576) KV[(size_t)bh * 576 + idx] = sum;
        else           KS[(size_t)bh * 72 + (idx - 576)] = sum;
    }
}

// ---------------- Kernel C: attn (f16 q in, f16 ao out) ----------------
__global__ void attn_kernel(const unsigned short* __restrict__ q, const float* __restrict__ KV,
                            const float* __restrict__ KS, unsigned short* __restrict__ aof) {
    const int y = blockIdx.x;
    const int h = blockIdx.y;
    const int b = blockIdx.z;
    const int col = threadIdx.x;

    float out[8] = {0.f};
    float den = 0.f;
    const int kvbase = (b * NH + h) * 8;

    for (int c = 0; c < 8; ++c) {
        const unsigned short* qc = q + ((size_t)(b * 64) + 8 * h + c) * LL;
        float q9[9];
#pragma unroll
        for (int dy = -1; dy <= 1; ++dy)
#pragma unroll
            for (int dx = -1; dx <= 1; ++dx) {
                const int yy = y + dy, xx = col + dx;
                const bool ok = (yy >= 0 && yy < HH && xx >= 0 && xx < WW);
                q9[(dy + 1) * 3 + (dx + 1)] = ok ? h2f(qc[yy * WW + xx]) : 0.f;
            }
        const float* kvr = KV + ((size_t)(kvbase + c) * 9) * 8;
        const float* ksr = KS + (size_t)(kvbase + c) * 9;
#pragma unroll
        for (int p = 0; p < 9; ++p) {
            const float qv = q9[p];
            den += qv * ksr[p];
#pragma unroll
            for (int cp = 0; cp < 8; ++cp) out[cp] += qv * kvr[p * 8 + cp];
        }
    }
    const float inv = 1.f / (den + EPSF);
    const int pix = y * WW + col;
#pragma unroll
    for (int cp = 0; cp < 8; ++cp)
        aof[((size_t)(b * 64) + h * 8 + cp) * LL + pix] = f2h_bits(out[cp] * inv);
}

// ---------------- Kernel W: pre-split proj_w into MFMA fragment layout (single f16) --
__global__ void wprep_kernel(const float* __restrict__ w, unsigned short* __restrict__ wfrag) {
    const int idx = blockIdx.x * 256 + threadIdx.x;   // 16*64*64 = 65536
    const int k  = idx & 63;
    const int co = (idx >> 6) & 63;
    const int ks = idx >> 12;
    const int kg = ks * 64 + k;
    const int ci = kg >> 4, tap = kg & 15;
    const float vv = (tap < 9) ? w[(co * 64 + ci) * 9 + tap] : 0.f;
    const int kx = (((k >> 3) ^ (co & 7)) << 3) | (k & 7);
    wfrag[((size_t)ks * 64 + co) * 64 + kx] = f2h_bits(vv);
}

// ---------------- Kernel D: 3x3 conv via MFMA; all-f16 operands; dbuf LDS ----------
// grid 1024 (XCD-chunk swizzled): block -> (b, row y, col-half), 64 pix.
// 16 ksteps of K=64 (4 ci). Per kstep: 9 ushort loads + 2 uint4 W + 10 ds_read
// + 8 MFMA. LDS = 2 x (8K plds + 8K wlds) = 32 KB -> all 4 blocks/CU resident.
#define CONV_PREFETCH(KS)                                                        \
    do {                                                                         \
        const unsigned short* src_ = aof + (size_t)((KS) * 4 + scis) * LL;       \
        pf0 = (oky0 && okxm) ? src_[offm - WW] : (unsigned short)0;              \
        pf1 = oky0 ? src_[off0 - WW] : (unsigned short)0;                        \
        pf2 = (oky0 && okxp) ? src_[offp - WW] : (unsigned short)0;              \
        pf3 = okxm ? src_[offm] : (unsigned short)0;                             \
        pf4 = src_[off0];                                                        \
        pf5 = okxp ? src_[offp] : (unsigned short)0;                             \
        pf6 = (oky2 && okxm) ? src_[offm + WW] : (unsigned short)0;              \
        pf7 = oky2 ? src_[off0 + WW] : (unsigned short)0;                        \
        pf8 = (oky2 && okxp) ? src_[offp + WW] : (unsigned short)0;              \
        const uint4* wsrc_ = (const uint4*)(wfrag + (size_t)(KS) * 4096);        \
        wf0 = wsrc_[tid];                                                        \
        wf1 = wsrc_[256 + tid];                                                  \
    } while (0)

__global__ __launch_bounds__(256) void conv_kernel(const unsigned short* __restrict__ aof,
                                                   const unsigned short* __restrict__ wfrag,
                                                   const float* __restrict__ bias,
                                                   float* __restrict__ out) {
    const int bid = blockIdx.x;
    const int swz = (bid & 7) * 128 + (bid >> 3);   // XCD-chunked
    const int b = swz >> 8;
    const int rem = swz & 255;
    const int y = rem >> 1;
    const int colbase = (rem & 1) * 64;
    const int tid = threadIdx.x;
    const int lane = tid & 63;
    const int wv = tid >> 6;
    const int rl = lane & 15;
    const int g  = lane >> 4;

    __shared__ unsigned short plds[2][64 * 64];   // 2 x 8192 B (P single f16)
    __shared__ unsigned short wlds[2][64 * 64];   // 2 x 8192 B (W single f16)

    f32x4 acc[4];
#pragma unroll
    for (int ct = 0; ct < 4; ++ct) acc[ct] = (f32x4)0.f;

    const int spix = tid & 63;       // staging pixel (local)
    const int scis = tid >> 6;       // staging ci-select 0..3

    // fixed staging geometry (aof base includes batch)
    const unsigned short* aofb = aof + (size_t)b * 64 * LL;
    const int xc   = colbase + spix;
    const int off0 = y * WW + xc;
    const int offm = off0 - 1;
    const int offp = off0 + 1;
    const bool oky0 = (y > 0);
    const bool oky2 = (y < HH - 1);
    const bool okxm = (xc > 0);
    const bool okxp = (xc < WW - 1);
    const int xs0 = (((2 * scis)     ^ (spix & 7)) << 3);
    const int xs1 = (((2 * scis + 1) ^ (spix & 7)) << 3);

    unsigned short pf0, pf1, pf2, pf3, pf4, pf5, pf6, pf7, pf8;
    uint4 wf0, wf1;

    {
        const unsigned short* aof_ = aofb;   // macro uses 'aof' name below via alias
        (void)aof_;
    }

#define aof aofb
    CONV_PREFETCH(0);
#undef aof

    for (int ks = 0; ks < 16; ++ks) {
        const int cur = ks & 1;
        // ---- unpack named regs -> LDS[cur] ----
        {
            unsigned short h16[16];
            h16[0] = pf0;  h16[1] = pf1;  h16[2] = pf2;
            h16[3] = pf3;  h16[4] = pf4;  h16[5] = pf5;
            h16[6] = pf6;  h16[7] = pf7;  h16[8] = pf8;
#pragma unroll
            for (int j = 9; j < 16; ++j) h16[j] = 0;
            *(u16x8*)&plds[cur][spix * 64 + xs0] = *(u16x8*)&h16[0];
            *(u16x8*)&plds[cur][spix * 64 + xs1] = *(u16x8*)&h16[8];
            uint4* wdst = (uint4*)&wlds[cur][0];
            wdst[tid]       = wf0;
            wdst[256 + tid] = wf1;
        }
        __syncthreads();
        if (ks < 15) {
#define aof aofb
            CONV_PREFETCH(ks + 1);   // flies under the MFMA phase
#undef aof
        }

        // ---- MFMA: 2 ksubs x 4 co-tiles (all single f16) ----
#pragma unroll
        for (int ksub = 0; ksub < 2; ++ksub) {
            const int xs = (((ksub * 4 + g) ^ (rl & 7)) << 3);
            const int row = wv * 16 + rl;
            const f16x8 bh = *(const f16x8*)&plds[cur][row * 64 + xs];
#pragma unroll
            for (int ct = 0; ct < 4; ++ct) {
                const int rowa = ct * 16 + rl;
                const f16x8 ah = *(const f16x8*)&wlds[cur][rowa * 64 + xs];
                acc[ct] = __builtin_amdgcn_mfma_f32_16x16x32_f16(ah, bh, acc[ct], 0, 0, 0);
            }
        }
    }

#pragma unroll
    for (int ct = 0; ct < 4; ++ct) {
        const int co_b = ct * 16 + g * 4;
        const int px = colbase + wv * 16 + rl;
#pragma unroll
        for (int j = 0; j < 4; ++j) {
            const int co = co_b + j;
            out[((size_t)b * 64 + co) * LL + y * WW + px] = acc[ct][j] + bias[co];
        }
    }
}

extern "C" void kernel_launch(void* const* d_in, const int* in_sizes, int n_in,
                              void* d_out, int out_size, void* d_ws, size_t ws_size,
                              hipStream_t stream) {
    const float* x      = (const float*)d_in[0];
    const float* qkv_w  = (const float*)d_in[1];
    const float* qkv_b  = (const float*)d_in[2];
    const float* proj_w = (const float*)d_in[3];
    const float* proj_b = (const float*)d_in[4];
    float* out = (float*)d_out;
    float* ws  = (float*)d_ws;

    const size_t n1 = (size_t)4 * 64 * LL;      // one B*C*L fp32 plane set
    unsigned short* qb = (unsigned short*)ws;   // f16, uses half of n1 region
    float* kb   = ws + n1;
    float* vb   = ws + 2 * n1;
    unsigned short* aof = (unsigned short*)(ws + 3 * n1);   // f16
    float* KV   = ws + 4 * n1;                  // 4*8*8*9*8 = 18432 floats
    float* KS   = KV + 4 * 8 * 8 * 9 * 8;       // 4*8*8*9  = 2304 floats
    float* KVp  = KS + 4 * 8 * 8 * 9;           // 32*32*648 = 663552 floats
    unsigned short* wfrag = (unsigned short*)(KVp + (size_t)32 * KVCHUNKS * 648);  // 65536 halfs

    wprep_kernel<<<256, 256, 0, stream>>>(proj_w, wfrag);
    qkv_kernel<<<dim3(128, 4, 3), 256, 0, stream>>>(x, qkv_w, qkv_b, qb, kb, vb);
    kv_kernel<<<dim3(KVCHUNKS, NH, 4), 256, 0, stream>>>(kb, vb, KVp);
    kv_finalize<<<32, 256, 0, stream>>>(KVp, KV, KS);
    attn_kernel<<<dim3(128, NH, 4), 128, 0, stream>>>(qb, KV, KS, aof);
    conv_kernel<<<1024, 256, 0, stream>>>(aof, wfrag, proj_b, out);
}

// Round 19
// 112.567 us; speedup vs baseline: 1.1462x; 1.1462x over previous
//
#include <hip/hip_runtime.h>
#include <hip/hip_fp16.h>

#define LL 16384
#define HH 128
#define WW 128
#define CC 64
#define NH 8
#define EPSF 1e-7f
#define KVCHUNKS 32

typedef __attribute__((ext_vector_type(8))) _Float16 f16x8;
typedef __attribute__((ext_vector_type(4))) float f32x4;
typedef __attribute__((ext_vector_type(8))) unsigned short u16x8;

static __device__ __forceinline__ unsigned short f2h_bits(float v) {
    const _Float16 h = (_Float16)v;
    unsigned short b;
    __builtin_memcpy(&b, &h, 2);
    return b;
}
static __device__ __forceinline__ float h2f_lo(unsigned int u) {
    _Float16 h;
    unsigned short s = (unsigned short)(u & 0xffffu);
    __builtin_memcpy(&h, &s, 2);
    return (float)h;
}
static __device__ __forceinline__ float h2f_hi(unsigned int u) {
    _Float16 h;
    unsigned short s = (unsigned short)(u >> 16);
    __builtin_memcpy(&h, &s, 2);
    return (float)h;
}

// ---------------- Kernel A: qkv 1x1 conv + bias (+relu on q,k) via MFMA hi/lo ----------
// q written as single f16 (feeds num/denom ratio in attn -> error largely cancels).
__global__ void qkv_kernel(const float* __restrict__ x, const float* __restrict__ w,
                           const float* __restrict__ bias,
                           unsigned short* __restrict__ q, float* __restrict__ k,
                           float* __restrict__ v) {
    const int pix0 = blockIdx.x * 128;
    const int b    = blockIdx.y;
    const int sec  = blockIdx.z;
    const int tid  = threadIdx.x;
    const int lane = tid & 63;
    const int wv   = tid >> 6;

    __shared__ _Float16 xh[128][72], xl[128][72];
    __shared__ _Float16 wh[64][72],  wl[64][72];

    {
        const float* xb = x + (size_t)b * CC * LL + pix0;
        for (int idx = tid; idx < 64 * 128; idx += 256) {
            const int ci = idx >> 7;
            const int px = idx & 127;
            const float vv = xb[(size_t)ci * LL + px];
            const _Float16 h = (_Float16)vv;
            xh[px][ci] = h;
            xl[px][ci] = (_Float16)(vv - (float)h);
        }
    }
    {
        const float* wsec = w + (size_t)sec * 64 * 64;
        for (int idx = tid; idx < 64 * 64; idx += 256) {
            const int co = idx >> 6;
            const int ci = idx & 63;
            const float vv = wsec[co * 64 + ci];
            const _Float16 h = (_Float16)vv;
            wh[co][ci] = h;
            wl[co][ci] = (_Float16)(vv - (float)h);
        }
    }
    __syncthreads();

    f32x4 acc[4][2];
#pragma unroll
    for (int ct = 0; ct < 4; ++ct)
#pragma unroll
        for (int pt = 0; pt < 2; ++pt) acc[ct][pt] = (f32x4)0.f;

    const int g8 = (lane >> 4) * 8;
    const int rl = lane & 15;

#pragma unroll
    for (int ks = 0; ks < 2; ++ks) {
        const int kb = ks * 32 + g8;
        f16x8 ah[4], al[4], bh[2], bl[2];
#pragma unroll
        for (int ct = 0; ct < 4; ++ct) {
            ah[ct] = *(const f16x8*)&wh[ct * 16 + rl][kb];
            al[ct] = *(const f16x8*)&wl[ct * 16 + rl][kb];
        }
#pragma unroll
        for (int pt = 0; pt < 2; ++pt) {
            bh[pt] = *(const f16x8*)&xh[wv * 32 + pt * 16 + rl][kb];
            bl[pt] = *(const f16x8*)&xl[wv * 32 + pt * 16 + rl][kb];
        }
#pragma unroll
        for (int ct = 0; ct < 4; ++ct)
#pragma unroll
            for (int pt = 0; pt < 2; ++pt) {
                acc[ct][pt] = __builtin_amdgcn_mfma_f32_16x16x32_f16(ah[ct], bh[pt], acc[ct][pt], 0, 0, 0);
                acc[ct][pt] = __builtin_amdgcn_mfma_f32_16x16x32_f16(ah[ct], bl[pt], acc[ct][pt], 0, 0, 0);
                acc[ct][pt] = __builtin_amdgcn_mfma_f32_16x16x32_f16(al[ct], bh[pt], acc[ct][pt], 0, 0, 0);
            }
    }

#pragma unroll
    for (int ct = 0; ct < 4; ++ct) {
        const int co_b = ct * 16 + (lane >> 4) * 4;
#pragma unroll
        for (int pt = 0; pt < 2; ++pt) {
            const int px = pix0 + wv * 32 + pt * 16 + rl;
#pragma unroll
            for (int j = 0; j < 4; ++j) {
                const int co = co_b + j;
                float val = acc[ct][pt][j] + bias[sec * 64 + co];
                if (sec == 0) {
                    val = fmaxf(val, 0.f);
                    q[((size_t)b * 64 + co) * LL + px] = f2h_bits(val);
                } else if (sec == 1) {
                    val = fmaxf(val, 0.f);
                    k[((size_t)b * 64 + co) * LL + px] = val;
                } else {
                    v[((size_t)b * 64 + co) * LL + px] = val;
                }
            }
        }
    }
}

// ---------------- Kernel B: KV/KS partials, K staged in LDS ----------------
__global__ void kv_kernel(const float* __restrict__ k, const float* __restrict__ v,
                          float* __restrict__ KVp) {
    const int chunk = blockIdx.x;
    const int h = blockIdx.y;
    const int b = blockIdx.z;
    const int tid = threadIdx.x;
    const int c  = tid >> 5;
    const int s  = tid & 31;
    const int half = s >> 4;
    const int sl   = s & 15;
    const int cpb  = half * 4;

    __shared__ float klds[8][6][130];

    {
        const float* kb = k + ((size_t)(b * 64) + 8 * h) * LL;
        for (int t = tid; t < 8 * 6 * 130; t += 256) {
            const int ch = t / 780;
            const int r1 = t - ch * 780;
            const int lr = r1 / 130;
            const int cx = r1 - lr * 130;
            const int gy = chunk * 4 + lr - 1;
            const int gx = cx - 1;
            const bool ok = (gy >= 0 && gy < HH && gx >= 0 && gx < WW);
            klds[ch][lr][cx] = ok ? kb[(size_t)ch * LL + gy * WW + gx] : 0.f;
        }
    }
    __syncthreads();

    const float* vb = v + ((size_t)(b * 64) + 8 * h + cpb) * LL;

    float kv4[9][4] = {{0.f}};
    float ks[9] = {0.f};

    for (int r = 0; r < 4; ++r) {
        const int y = chunk * 4 + r;
        for (int g = 0; g < 8; ++g) {
            const int col = g * 16 + sl;
            float vv[4];
#pragma unroll
            for (int cp = 0; cp < 4; ++cp) vv[cp] = vb[(size_t)cp * LL + y * WW + col];
            float k9[9];
#pragma unroll
            for (int dy = 0; dy < 3; ++dy)
#pragma unroll
                for (int dx = 0; dx < 3; ++dx)
                    k9[dy * 3 + dx] = klds[c][r + dy][col + dx];
#pragma unroll
            for (int p = 0; p < 9; ++p) {
                ks[p] += k9[p];
#pragma unroll
                for (int cp = 0; cp < 4; ++cp)
                    kv4[p][cp] = fmaf(k9[p], vv[cp], kv4[p][cp]);
            }
        }
    }

#pragma unroll
    for (int p = 0; p < 9; ++p) {
#pragma unroll
        for (int m = 8; m >= 1; m >>= 1) ks[p] += __shfl_xor(ks[p], m);
#pragma unroll
        for (int cp = 0; cp < 4; ++cp) {
#pragma unroll
            for (int m = 8; m >= 1; m >>= 1) kv4[p][cp] += __shfl_xor(kv4[p][cp], m);
        }
    }

    if (sl == 0) {
        float* dst = KVp + (((size_t)(b * NH + h) * KVCHUNKS) + chunk) * 648;
#pragma unroll
        for (int p = 0; p < 9; ++p) {
#pragma unroll
            for (int cp = 0; cp < 4; ++cp)
                dst[(c * 9 + p) * 8 + cpb + cp] = kv4[p][cp];
            if (half == 0) dst[576 + c * 9 + p] = ks[p];
        }
    }
}

// ---------------- Kernel B2: reduce 32 chunk-partials -> KV, KS ----------------
__global__ void kv_finalize(const float* __restrict__ KVp,
                            float* __restrict__ KV, float* __restrict__ KS) {
    const int bh = blockIdx.x;
    const float* src = KVp + (size_t)bh * KVCHUNKS * 648;
    for (int idx = threadIdx.x; idx < 648; idx += 256) {
        float s0 = 0.f, s1 = 0.f, s2 = 0.f, s3 = 0.f;
#pragma unroll
        for (int ch = 0; ch < KVCHUNKS; ch += 4) {
            s0 += src[(ch + 0) * 648 + idx];
            s1 += src[(ch + 1) * 648 + idx];
            s2 += src[(ch + 2) * 648 + idx];
            s3 += src[(ch + 3) * 648 + idx];
        }
        const float sum = (s0 + s1) + (s2 + s3);
        if (idx < 576) KV[(size_t)bh * 576 + idx] = sum;
        else           KS[(size_t)bh * 72 + (idx - 576)] = sum;
    }
}

// ---------------- Kernel C: attn, pixel-pair per thread, uint transport ----------
// grid (128 rows, NH, B), block 64. Thread t -> pixels (2t, 2t+1).
// Per channel: 3 rows x 3 aligned uint loads cover cols [2t-2, 2t+3]; the two
// pixel windows use halves [1..4]. 8 packed-uint stores. Bit-identical numerics
// to scalar version (same f16 q values, same FMA order per pixel).
__global__ void attn_kernel(const unsigned short* __restrict__ q, const float* __restrict__ KV,
                            const float* __restrict__ KS, unsigned int* __restrict__ aofu) {
    const int y = blockIdx.x;
    const int h = blockIdx.y;
    const int b = blockIdx.z;
    const int t = threadIdx.x;   // 0..63

    float out0[8] = {0.f}, out1[8] = {0.f};
    float den0 = 0.f, den1 = 0.f;
    const int kvbase = (b * NH + h) * 8;
    const bool tlo = (t > 0), thi = (t < 63);

    for (int c = 0; c < 8; ++c) {
        const unsigned short* qc = q + ((size_t)(b * 64) + 8 * h + c) * LL;
        float qw[3][6];
#pragma unroll
        for (int dy = 0; dy < 3; ++dy) {
            const int yy = y + dy - 1;
            const bool yok = (yy >= 0 && yy < HH);
            const unsigned short* row = qc + yy * WW;
            const unsigned int u0 = (yok && tlo) ? *(const unsigned int*)(row + 2 * t - 2) : 0u;
            const unsigned int u1 = yok ? *(const unsigned int*)(row + 2 * t) : 0u;
            const unsigned int u2 = (yok && thi) ? *(const unsigned int*)(row + 2 * t + 2) : 0u;
            qw[dy][0] = h2f_lo(u0);  qw[dy][1] = h2f_hi(u0);
            qw[dy][2] = h2f_lo(u1);  qw[dy][3] = h2f_hi(u1);
            qw[dy][4] = h2f_lo(u2);  qw[dy][5] = h2f_hi(u2);
        }
        const float* kvr = KV + ((size_t)(kvbase + c) * 9) * 8;  // wave-uniform
        const float* ksr = KS + (size_t)(kvbase + c) * 9;
#pragma unroll
        for (int dy = 0; dy < 3; ++dy)
#pragma unroll
            for (int dx = 0; dx < 3; ++dx) {
                const int p = dy * 3 + dx;
                const float q0 = qw[dy][1 + dx];   // window of pixel 2t
                const float q1 = qw[dy][2 + dx];   // window of pixel 2t+1
                const float ksv = ksr[p];
                den0 = fmaf(q0, ksv, den0);
                den1 = fmaf(q1, ksv, den1);
#pragma unroll
                for (int cp = 0; cp < 8; ++cp) {
                    const float kvv = kvr[p * 8 + cp];
                    out0[cp] = fmaf(q0, kvv, out0[cp]);
                    out1[cp] = fmaf(q1, kvv, out1[cp]);
                }
            }
    }
    const float inv0 = 1.f / (den0 + EPSF);
    const float inv1 = 1.f / (den1 + EPSF);
    const int pixu = y * (WW / 2) + t;   // uint index within the channel plane
#pragma unroll
    for (int cp = 0; cp < 8; ++cp) {
        const unsigned int lo = f2h_bits(out0[cp] * inv0);
        const unsigned int hi = f2h_bits(out1[cp] * inv1);
        aofu[((size_t)(b * 64) + h * 8 + cp) * (LL / 2) + pixu] = lo | (hi << 16);
    }
}

// ---------------- Kernel W: pre-split proj_w into MFMA fragment layout (single f16) --
__global__ void wprep_kernel(const float* __restrict__ w, unsigned short* __restrict__ wfrag) {
    const int idx = blockIdx.x * 256 + threadIdx.x;   // 16*64*64 = 65536
    const int k  = idx & 63;
    const int co = (idx >> 6) & 63;
    const int ks = idx >> 12;
    const int kg = ks * 64 + k;
    const int ci = kg >> 4, tap = kg & 15;
    const float vv = (tap < 9) ? w[(co * 64 + ci) * 9 + tap] : 0.f;
    const int kx = (((k >> 3) ^ (co & 7)) << 3) | (k & 7);
    wfrag[((size_t)ks * 64 + co) * 64 + kx] = f2h_bits(vv);
}

// ---------------- Kernel D: 3x3 conv via MFMA; all-f16 operands; dbuf LDS ----------
// grid 1024 (XCD-chunk swizzled): block -> (b, row y, col-half), 64 pix.
// 16 ksteps of K=64 (4 ci). Per kstep: 9 ushort loads + 2 uint4 W + 10 ds_read
// + 8 MFMA. LDS = 2 x (8K plds + 8K wlds) = 32 KB -> all 4 blocks/CU resident.
#define CONV_PREFETCH(KS)                                                        \
    do {                                                                         \
        const unsigned short* src_ = aofb + (size_t)((KS) * 4 + scis) * LL;      \
        pf0 = (oky0 && okxm) ? src_[offm - WW] : (unsigned short)0;              \
        pf1 = oky0 ? src_[off0 - WW] : (unsigned short)0;                        \
        pf2 = (oky0 && okxp) ? src_[offp - WW] : (unsigned short)0;              \
        pf3 = okxm ? src_[offm] : (unsigned short)0;                             \
        pf4 = src_[off0];                                                        \
        pf5 = okxp ? src_[offp] : (unsigned short)0;                             \
        pf6 = (oky2 && okxm) ? src_[offm + WW] : (unsigned short)0;              \
        pf7 = oky2 ? src_[off0 + WW] : (unsigned short)0;                        \
        pf8 = (oky2 && okxp) ? src_[offp + WW] : (unsigned short)0;              \
        const uint4* wsrc_ = (const uint4*)(wfrag + (size_t)(KS) * 4096);        \
        wf0 = wsrc_[tid];                                                        \
        wf1 = wsrc_[256 + tid];                                                  \
    } while (0)

__global__ __launch_bounds__(256) void conv_kernel(const unsigned short* __restrict__ aof,
                                                   const unsigned short* __restrict__ wfrag,
                                                   const float* __restrict__ bias,
                                                   float* __restrict__ out) {
    const int bid = blockIdx.x;
    const int swz = (bid & 7) * 128 + (bid >> 3);   // XCD-chunked
    const int b = swz >> 8;
    const int rem = swz & 255;
    const int y = rem >> 1;
    const int colbase = (rem & 1) * 64;
    const int tid = threadIdx.x;
    const int lane = tid & 63;
    const int wv = tid >> 6;
    const int rl = lane & 15;
    const int g  = lane >> 4;

    __shared__ unsigned short plds[2][64 * 64];   // 2 x 8192 B (P single f16)
    __shared__ unsigned short wlds[2][64 * 64];   // 2 x 8192 B (W single f16)

    f32x4 acc[4];
#pragma unroll
    for (int ct = 0; ct < 4; ++ct) acc[ct] = (f32x4)0.f;

    const int spix = tid & 63;       // staging pixel (local)
    const int scis = tid >> 6;       // staging ci-select 0..3

    // fixed staging geometry
    const unsigned short* aofb = aof + (size_t)b * 64 * LL;
    const int xc   = colbase + spix;
    const int off0 = y * WW + xc;
    const int offm = off0 - 1;
    const int offp = off0 + 1;
    const bool oky0 = (y > 0);
    const bool oky2 = (y < HH - 1);
    const bool okxm = (xc > 0);
    const bool okxp = (xc < WW - 1);
    const int xs0 = (((2 * scis)     ^ (spix & 7)) << 3);
    const int xs1 = (((2 * scis + 1) ^ (spix & 7)) << 3);

    unsigned short pf0, pf1, pf2, pf3, pf4, pf5, pf6, pf7, pf8;
    uint4 wf0, wf1;

    CONV_PREFETCH(0);

    for (int ks = 0; ks < 16; ++ks) {
        const int cur = ks & 1;
        // ---- unpack named regs -> LDS[cur] ----
        {
            unsigned short h16[16];
            h16[0] = pf0;  h16[1] = pf1;  h16[2] = pf2;
            h16[3] = pf3;  h16[4] = pf4;  h16[5] = pf5;
            h16[6] = pf6;  h16[7] = pf7;  h16[8] = pf8;
#pragma unroll
            for (int j = 9; j < 16; ++j) h16[j] = 0;
            *(u16x8*)&plds[cur][spix * 64 + xs0] = *(u16x8*)&h16[0];
            *(u16x8*)&plds[cur][spix * 64 + xs1] = *(u16x8*)&h16[8];
            uint4* wdst = (uint4*)&wlds[cur][0];
            wdst[tid]       = wf0;
            wdst[256 + tid] = wf1;
        }
        __syncthreads();
        if (ks < 15) CONV_PREFETCH(ks + 1);   // flies under the MFMA phase

        // ---- MFMA: 2 ksubs x 4 co-tiles (all single f16) ----
#pragma unroll
        for (int ksub = 0; ksub < 2; ++ksub) {
            const int xs = (((ksub * 4 + g) ^ (rl & 7)) << 3);
            const int row = wv * 16 + rl;
            const f16x8 bh = *(const f16x8*)&plds[cur][row * 64 + xs];
#pragma unroll
            for (int ct = 0; ct < 4; ++ct) {
                const int rowa = ct * 16 + rl;
                const f16x8 ah = *(const f16x8*)&wlds[cur][rowa * 64 + xs];
                acc[ct] = __builtin_amdgcn_mfma_f32_16x16x32_f16(ah, bh, acc[ct], 0, 0, 0);
            }
        }
    }

#pragma unroll
    for (int ct = 0; ct < 4; ++ct) {
        const int co_b = ct * 16 + g * 4;
        const int px = colbase + wv * 16 + rl;
#pragma unroll
        for (int j = 0; j < 4; ++j) {
            const int co = co_b + j;
            out[((size_t)b * 64 + co) * LL + y * WW + px] = acc[ct][j] + bias[co];
        }
    }
}

extern "C" void kernel_launch(void* const* d_in, const int* in_sizes, int n_in,
                              void* d_out, int out_size, void* d_ws, size_t ws_size,
                              hipStream_t stream) {
    const float* x      = (const float*)d_in[0];
    const float* qkv_w  = (const float*)d_in[1];
    const float* qkv_b  = (const float*)d_in[2];
    const float* proj_w = (const float*)d_in[3];
    const float* proj_b = (const float*)d_in[4];
    float* out = (float*)d_out;
    float* ws  = (float*)d_ws;

    const size_t n1 = (size_t)4 * 64 * LL;      // one B*C*L fp32 plane set
    unsigned short* qb = (unsigned short*)ws;   // f16
    float* kb   = ws + n1;
    float* vb   = ws + 2 * n1;
    unsigned short* aof = (unsigned short*)(ws + 3 * n1);   // f16
    float* KV   = ws + 4 * n1;                  // 4*8*8*9*8 = 18432 floats
    float* KS   = KV + 4 * 8 * 8 * 9 * 8;       // 4*8*8*9  = 2304 floats
    float* KVp  = KS + 4 * 8 * 8 * 9;           // 32*32*648 = 663552 floats
    unsigned short* wfrag = (unsigned short*)(KVp + (size_t)32 * KVCHUNKS * 648);  // 65536 halfs

    wprep_kernel<<<256, 256, 0, stream>>>(proj_w, wfrag);
    qkv_kernel<<<dim3(128, 4, 3), 256, 0, stream>>>(x, qkv_w, qkv_b, qb, kb, vb);
    kv_kernel<<<dim3(KVCHUNKS, NH, 4), 256, 0, stream>>>(kb, vb, KVp);
    kv_finalize<<<32, 256, 0, stream>>>(KVp, KV, KS);
    attn_kernel<<<dim3(128, NH, 4), 64, 0, stream>>>(qb, KV, KS, (unsigned int*)aof);
    conv_kernel<<<1024, 256, 0, stream>>>(aof, wfrag, proj_b, out);
}

// Round 20
// 103.302 us; speedup vs baseline: 1.2490x; 1.0897x over previous
//
#include <hip/hip_runtime.h>
#include <hip/hip_fp16.h>

#define LL 16384
#define HH 128
#define WW 128
#define CC 64
#define NH 8
#define EPSF 1e-7f
#define KVCHUNKS 32

typedef __attribute__((ext_vector_type(8))) _Float16 f16x8;
typedef __attribute__((ext_vector_type(4))) float f32x4;
typedef __attribute__((ext_vector_type(8))) unsigned short u16x8;

static __device__ __forceinline__ unsigned short f2h_bits(float v) {
    const _Float16 h = (_Float16)v;
    unsigned short b;
    __builtin_memcpy(&b, &h, 2);
    return b;
}
static __device__ __forceinline__ float h2f_u16(unsigned short s) {
    _Float16 h;
    __builtin_memcpy(&h, &s, 2);
    return (float)h;
}
static __device__ __forceinline__ float h2f_lo(unsigned int u) {
    return h2f_u16((unsigned short)(u & 0xffffu));
}
static __device__ __forceinline__ float h2f_hi(unsigned int u) {
    return h2f_u16((unsigned short)(u >> 16));
}

// ---------------- Kernel A: qkv 1x1 conv + bias (+relu on q,k) via MFMA hi/lo ----------
// q,k,v all written as f16 (write-BW-bound kernel: 201->100 MB).
__global__ void qkv_kernel(const float* __restrict__ x, const float* __restrict__ w,
                           const float* __restrict__ bias,
                           unsigned short* __restrict__ q, unsigned short* __restrict__ k,
                           unsigned short* __restrict__ v) {
    const int pix0 = blockIdx.x * 128;
    const int b    = blockIdx.y;
    const int sec  = blockIdx.z;
    const int tid  = threadIdx.x;
    const int lane = tid & 63;
    const int wv   = tid >> 6;

    __shared__ _Float16 xh[128][72], xl[128][72];
    __shared__ _Float16 wh[64][72],  wl[64][72];

    {
        const float* xb = x + (size_t)b * CC * LL + pix0;
        for (int idx = tid; idx < 64 * 128; idx += 256) {
            const int ci = idx >> 7;
            const int px = idx & 127;
            const float vv = xb[(size_t)ci * LL + px];
            const _Float16 h = (_Float16)vv;
            xh[px][ci] = h;
            xl[px][ci] = (_Float16)(vv - (float)h);
        }
    }
    {
        const float* wsec = w + (size_t)sec * 64 * 64;
        for (int idx = tid; idx < 64 * 64; idx += 256) {
            const int co = idx >> 6;
            const int ci = idx & 63;
            const float vv = wsec[co * 64 + ci];
            const _Float16 h = (_Float16)vv;
            wh[co][ci] = h;
            wl[co][ci] = (_Float16)(vv - (float)h);
        }
    }
    __syncthreads();

    f32x4 acc[4][2];
#pragma unroll
    for (int ct = 0; ct < 4; ++ct)
#pragma unroll
        for (int pt = 0; pt < 2; ++pt) acc[ct][pt] = (f32x4)0.f;

    const int g8 = (lane >> 4) * 8;
    const int rl = lane & 15;

#pragma unroll
    for (int ks = 0; ks < 2; ++ks) {
        const int kb = ks * 32 + g8;
        f16x8 ah[4], al[4], bh[2], bl[2];
#pragma unroll
        for (int ct = 0; ct < 4; ++ct) {
            ah[ct] = *(const f16x8*)&wh[ct * 16 + rl][kb];
            al[ct] = *(const f16x8*)&wl[ct * 16 + rl][kb];
        }
#pragma unroll
        for (int pt = 0; pt < 2; ++pt) {
            bh[pt] = *(const f16x8*)&xh[wv * 32 + pt * 16 + rl][kb];
            bl[pt] = *(const f16x8*)&xl[wv * 32 + pt * 16 + rl][kb];
        }
#pragma unroll
        for (int ct = 0; ct < 4; ++ct)
#pragma unroll
            for (int pt = 0; pt < 2; ++pt) {
                acc[ct][pt] = __builtin_amdgcn_mfma_f32_16x16x32_f16(ah[ct], bh[pt], acc[ct][pt], 0, 0, 0);
                acc[ct][pt] = __builtin_amdgcn_mfma_f32_16x16x32_f16(ah[ct], bl[pt], acc[ct][pt], 0, 0, 0);
                acc[ct][pt] = __builtin_amdgcn_mfma_f32_16x16x32_f16(al[ct], bh[pt], acc[ct][pt], 0, 0, 0);
            }
    }

    unsigned short* dst = (sec == 0) ? q : (sec == 1) ? k : v;
    const bool do_relu = (sec < 2);
#pragma unroll
    for (int ct = 0; ct < 4; ++ct) {
        const int co_b = ct * 16 + (lane >> 4) * 4;
#pragma unroll
        for (int pt = 0; pt < 2; ++pt) {
            const int px = pix0 + wv * 32 + pt * 16 + rl;
#pragma unroll
            for (int j = 0; j < 4; ++j) {
                const int co = co_b + j;
                float val = acc[ct][pt][j] + bias[sec * 64 + co];
                if (do_relu) val = fmaxf(val, 0.f);
                dst[((size_t)b * 64 + co) * LL + px] = f2h_bits(val);
            }
        }
    }
}

// ---------------- Kernel B: KV/KS partials, f16 k/v in, K staged in LDS (f32) -------
__global__ void kv_kernel(const unsigned short* __restrict__ k,
                          const unsigned short* __restrict__ v,
                          float* __restrict__ KVp) {
    const int chunk = blockIdx.x;
    const int h = blockIdx.y;
    const int b = blockIdx.z;
    const int tid = threadIdx.x;
    const int c  = tid >> 5;
    const int s  = tid & 31;
    const int half = s >> 4;
    const int sl   = s & 15;
    const int cpb  = half * 4;

    __shared__ float klds[8][6][130];

    {
        const unsigned short* kb = k + ((size_t)(b * 64) + 8 * h) * LL;
        for (int t = tid; t < 8 * 6 * 130; t += 256) {
            const int ch = t / 780;
            const int r1 = t - ch * 780;
            const int lr = r1 / 130;
            const int cx = r1 - lr * 130;
            const int gy = chunk * 4 + lr - 1;
            const int gx = cx - 1;
            const bool ok = (gy >= 0 && gy < HH && gx >= 0 && gx < WW);
            klds[ch][lr][cx] = ok ? h2f_u16(kb[(size_t)ch * LL + gy * WW + gx]) : 0.f;
        }
    }
    __syncthreads();

    const unsigned short* vb = v + ((size_t)(b * 64) + 8 * h + cpb) * LL;

    float kv4[9][4] = {{0.f}};
    float ks[9] = {0.f};

    for (int r = 0; r < 4; ++r) {
        const int y = chunk * 4 + r;
        for (int g = 0; g < 8; ++g) {
            const int col = g * 16 + sl;
            float vv[4];
#pragma unroll
            for (int cp = 0; cp < 4; ++cp) vv[cp] = h2f_u16(vb[(size_t)cp * LL + y * WW + col]);
            float k9[9];
#pragma unroll
            for (int dy = 0; dy < 3; ++dy)
#pragma unroll
                for (int dx = 0; dx < 3; ++dx)
                    k9[dy * 3 + dx] = klds[c][r + dy][col + dx];
#pragma unroll
            for (int p = 0; p < 9; ++p) {
                ks[p] += k9[p];
#pragma unroll
                for (int cp = 0; cp < 4; ++cp)
                    kv4[p][cp] = fmaf(k9[p], vv[cp], kv4[p][cp]);
            }
        }
    }

#pragma unroll
    for (int p = 0; p < 9; ++p) {
#pragma unroll
        for (int m = 8; m >= 1; m >>= 1) ks[p] += __shfl_xor(ks[p], m);
#pragma unroll
        for (int cp = 0; cp < 4; ++cp) {
#pragma unroll
            for (int m = 8; m >= 1; m >>= 1) kv4[p][cp] += __shfl_xor(kv4[p][cp], m);
        }
    }

    if (sl == 0) {
        float* dst = KVp + (((size_t)(b * NH + h) * KVCHUNKS) + chunk) * 648;
#pragma unroll
        for (int p = 0; p < 9; ++p) {
#pragma unroll
            for (int cp = 0; cp < 4; ++cp)
                dst[(c * 9 + p) * 8 + cpb + cp] = kv4[p][cp];
            if (half == 0) dst[576 + c * 9 + p] = ks[p];
        }
    }
}

// ---------------- Kernel B2: reduce 32 chunk-partials -> KV, KS ----------------
__global__ void kv_finalize(const float* __restrict__ KVp,
                            float* __restrict__ KV, float* __restrict__ KS) {
    const int bh = blockIdx.x;
    const float* src = KVp + (size_t)bh * KVCHUNKS * 648;
    for (int idx = threadIdx.x; idx < 648; idx += 256) {
        float s0 = 0.f, s1 = 0.f, s2 = 0.f, s3 = 0.f;
#pragma unroll
        for (int ch = 0; ch < KVCHUNKS; ch += 4) {
            s0 += src[(ch + 0) * 648 + idx];
            s1 += src[(ch + 1) * 648 + idx];
            s2 += src[(ch + 2) * 648 + idx];
            s3 += src[(ch + 3) * 648 + idx];
        }
        const float sum = (s0 + s1) + (s2 + s3);
        if (idx < 576) KV[(size_t)bh * 576 + idx] = sum;
        else           KS[(size_t)bh * 72 + (idx - 576)] = sum;
    }
}

// ---------------- Kernel C: attn, pixel-pair per thread, uint transport ----------
__global__ void attn_kernel(const unsigned short* __restrict__ q, const float* __restrict__ KV,
                            const float* __restrict__ KS, unsigned int* __restrict__ aofu) {
    const int y = blockIdx.x;
    const int h = blockIdx.y;
    const int b = blockIdx.z;
    const int t = threadIdx.x;   // 0..63

    float out0[8] = {0.f}, out1[8] = {0.f};
    float den0 = 0.f, den1 = 0.f;
    const int kvbase = (b * NH + h) * 8;
    const bool tlo = (t > 0), thi = (t < 63);

    for (int c = 0; c < 8; ++c) {
        const unsigned short* qc = q + ((size_t)(b * 64) + 8 * h + c) * LL;
        float qw[3][6];
#pragma unroll
        for (int dy = 0; dy < 3; ++dy) {
            const int yy = y + dy - 1;
            const bool yok = (yy >= 0 && yy < HH);
            const unsigned short* row = qc + yy * WW;
            const unsigned int u0 = (yok && tlo) ? *(const unsigned int*)(row + 2 * t - 2) : 0u;
            const unsigned int u1 = yok ? *(const unsigned int*)(row + 2 * t) : 0u;
            const unsigned int u2 = (yok && thi) ? *(const unsigned int*)(row + 2 * t + 2) : 0u;
            qw[dy][0] = h2f_lo(u0);  qw[dy][1] = h2f_hi(u0);
            qw[dy][2] = h2f_lo(u1);  qw[dy][3] = h2f_hi(u1);
            qw[dy][4] = h2f_lo(u2);  qw[dy][5] = h2f_hi(u2);
        }
        const float* kvr = KV + ((size_t)(kvbase + c) * 9) * 8;  // wave-uniform
        const float* ksr = KS + (size_t)(kvbase + c) * 9;
#pragma unroll
        for (int dy = 0; dy < 3; ++dy)
#pragma unroll
            for (int dx = 0; dx < 3; ++dx) {
                const int p = dy * 3 + dx;
                const float q0 = qw[dy][1 + dx];
                const float q1 = qw[dy][2 + dx];
                const float ksv = ksr[p];
                den0 = fmaf(q0, ksv, den0);
                den1 = fmaf(q1, ksv, den1);
#pragma unroll
                for (int cp = 0; cp < 8; ++cp) {
                    const float kvv = kvr[p * 8 + cp];
                    out0[cp] = fmaf(q0, kvv, out0[cp]);
                    out1[cp] = fmaf(q1, kvv, out1[cp]);
                }
            }
    }
    const float inv0 = 1.f / (den0 + EPSF);
    const float inv1 = 1.f / (den1 + EPSF);
    const int pixu = y * (WW / 2) + t;
#pragma unroll
    for (int cp = 0; cp < 8; ++cp) {
        const unsigned int lo = f2h_bits(out0[cp] * inv0);
        const unsigned int hi = f2h_bits(out1[cp] * inv1);
        aofu[((size_t)(b * 64) + h * 8 + cp) * (LL / 2) + pixu] = lo | (hi << 16);
    }
}

// ---------------- Kernel W: pre-split proj_w into MFMA fragment layout (single f16) --
__global__ void wprep_kernel(const float* __restrict__ w, unsigned short* __restrict__ wfrag) {
    const int idx = blockIdx.x * 256 + threadIdx.x;   // 16*64*64 = 65536
    const int k  = idx & 63;
    const int co = (idx >> 6) & 63;
    const int ks = idx >> 12;
    const int kg = ks * 64 + k;
    const int ci = kg >> 4, tap = kg & 15;
    const float vv = (tap < 9) ? w[(co * 64 + ci) * 9 + tap] : 0.f;
    const int kx = (((k >> 3) ^ (co & 7)) << 3) | (k & 7);
    wfrag[((size_t)ks * 64 + co) * 64 + kx] = f2h_bits(vv);
}

// ---------------- Kernel D: 3x3 conv via MFMA; all-f16 operands; dbuf LDS ----------
#define CONV_PREFETCH(KS)                                                        \
    do {                                                                         \
        const unsigned short* src_ = aofb + (size_t)((KS) * 4 + scis) * LL;      \
        pf0 = (oky0 && okxm) ? src_[offm - WW] : (unsigned short)0;              \
        pf1 = oky0 ? src_[off0 - WW] : (unsigned short)0;                        \
        pf2 = (oky0 && okxp) ? src_[offp - WW] : (unsigned short)0;              \
        pf3 = okxm ? src_[offm] : (unsigned short)0;                             \
        pf4 = src_[off0];                                                        \
        pf5 = okxp ? src_[offp] : (unsigned short)0;                             \
        pf6 = (oky2 && okxm) ? src_[offm + WW] : (unsigned short)0;              \
        pf7 = oky2 ? src_[off0 + WW] : (unsigned short)0;                        \
        pf8 = (oky2 && okxp) ? src_[offp + WW] : (unsigned short)0;              \
        const uint4* wsrc_ = (const uint4*)(wfrag + (size_t)(KS) * 4096);        \
        wf0 = wsrc_[tid];                                                        \
        wf1 = wsrc_[256 + tid];                                                  \
    } while (0)

__global__ __launch_bounds__(256) void conv_kernel(const unsigned short* __restrict__ aof,
                                                   const unsigned short* __restrict__ wfrag,
                                                   const float* __restrict__ bias,
                                                   float* __restrict__ out) {
    const int bid = blockIdx.x;
    const int swz = (bid & 7) * 128 + (bid >> 3);   // XCD-chunked
    const int b = swz >> 8;
    const int rem = swz & 255;
    const int y = rem >> 1;
    const int colbase = (rem & 1) * 64;
    const int tid = threadIdx.x;
    const int lane = tid & 63;
    const int wv = tid >> 6;
    const int rl = lane & 15;
    const int g  = lane >> 4;

    __shared__ unsigned short plds[2][64 * 64];   // 2 x 8192 B (P single f16)
    __shared__ unsigned short wlds[2][64 * 64];   // 2 x 8192 B (W single f16)

    f32x4 acc[4];
#pragma unroll
    for (int ct = 0; ct < 4; ++ct) acc[ct] = (f32x4)0.f;

    const int spix = tid & 63;
    const int scis = tid >> 6;

    const unsigned short* aofb = aof + (size_t)b * 64 * LL;
    const int xc   = colbase + spix;
    const int off0 = y * WW + xc;
    const int offm = off0 - 1;
    const int offp = off0 + 1;
    const bool oky0 = (y > 0);
    const bool oky2 = (y < HH - 1);
    const bool okxm = (xc > 0);
    const bool okxp = (xc < WW - 1);
    const int xs0 = (((2 * scis)     ^ (spix & 7)) << 3);
    const int xs1 = (((2 * scis + 1) ^ (spix & 7)) << 3);

    unsigned short pf0, pf1, pf2, pf3, pf4, pf5, pf6, pf7, pf8;
    uint4 wf0, wf1;

    CONV_PREFETCH(0);

    for (int ks = 0; ks < 16; ++ks) {
        const int cur = ks & 1;
        {
            unsigned short h16[16];
            h16[0] = pf0;  h16[1] = pf1;  h16[2] = pf2;
            h16[3] = pf3;  h16[4] = pf4;  h16[5] = pf5;
            h16[6] = pf6;  h16[7] = pf7;  h16[8] = pf8;
#pragma unroll
            for (int j = 9; j < 16; ++j) h16[j] = 0;
            *(u16x8*)&plds[cur][spix * 64 + xs0] = *(u16x8*)&h16[0];
            *(u16x8*)&plds[cur][spix * 64 + xs1] = *(u16x8*)&h16[8];
            uint4* wdst = (uint4*)&wlds[cur][0];
            wdst[tid]       = wf0;
            wdst[256 + tid] = wf1;
        }
        __syncthreads();
        if (ks < 15) CONV_PREFETCH(ks + 1);

#pragma unroll
        for (int ksub = 0; ksub < 2; ++ksub) {
            const int xs = (((ksub * 4 + g) ^ (rl & 7)) << 3);
            const int row = wv * 16 + rl;
            const f16x8 bh = *(const f16x8*)&plds[cur][row * 64 + xs];
#pragma unroll
            for (int ct = 0; ct < 4; ++ct) {
                const int rowa = ct * 16 + rl;
                const f16x8 ah = *(const f16x8*)&wlds[cur][rowa * 64 + xs];
                acc[ct] = __builtin_amdgcn_mfma_f32_16x16x32_f16(ah, bh, acc[ct], 0, 0, 0);
            }
        }
    }

#pragma unroll
    for (int ct = 0; ct < 4; ++ct) {
        const int co_b = ct * 16 + g * 4;
        const int px = colbase + wv * 16 + rl;
#pragma unroll
        for (int j = 0; j < 4; ++j) {
            const int co = co_b + j;
            out[((size_t)b * 64 + co) * LL + y * WW + px] = acc[ct][j] + bias[co];
        }
    }
}

extern "C" void kernel_launch(void* const* d_in, const int* in_sizes, int n_in,
                              void* d_out, int out_size, void* d_ws, size_t ws_size,
                              hipStream_t stream) {
    const float* x      = (const float*)d_in[0];
    const float* qkv_w  = (const float*)d_in[1];
    const float* qkv_b  = (const float*)d_in[2];
    const float* proj_w = (const float*)d_in[3];
    const float* proj_b = (const float*)d_in[4];
    float* out = (float*)d_out;
    float* ws  = (float*)d_ws;

    const size_t n1 = (size_t)4 * 64 * LL;      // one B*C*L fp32 plane set
    unsigned short* qb  = (unsigned short*)ws;          // f16
    unsigned short* kb  = (unsigned short*)(ws + n1);   // f16
    unsigned short* vb  = (unsigned short*)(ws + 2 * n1); // f16
    unsigned short* aof = (unsigned short*)(ws + 3 * n1); // f16
    float* KV   = ws + 4 * n1;                  // 4*8*8*9*8 = 18432 floats
    float* KS   = KV + 4 * 8 * 8 * 9 * 8;       // 4*8*8*9  = 2304 floats
    float* KVp  = KS + 4 * 8 * 8 * 9;           // 32*32*648 = 663552 floats
    unsigned short* wfrag = (unsigned short*)(KVp + (size_t)32 * KVCHUNKS * 648);  // 65536 halfs

    wprep_kernel<<<256, 256, 0, stream>>>(proj_w, wfrag);
    qkv_kernel<<<dim3(128, 4, 3), 256, 0, stream>>>(x, qkv_w, qkv_b, qb, kb, vb);
    kv_kernel<<<dim3(KVCHUNKS, NH, 4), 256, 0, stream>>>(kb, vb, KVp);
    kv_finalize<<<32, 256, 0, stream>>>(KVp, KV, KS);
    attn_kernel<<<dim3(128, NH, 4), 64, 0, stream>>>(qb, KV, KS, (unsigned int*)aof);
    conv_kernel<<<1024, 256, 0, stream>>>(aof, wfrag, proj_b, out);
}

// Round 21
// 100.846 us; speedup vs baseline: 1.2794x; 1.0244x over previous
//
#include <hip/hip_runtime.h>
#include <hip/hip_fp16.h>

#define LL 16384
#define HH 128
#define WW 128
#define CC 64
#define NH 8
#define EPSF 1e-7f
#define KVCHUNKS 32

typedef __attribute__((ext_vector_type(8))) _Float16 f16x8;
typedef __attribute__((ext_vector_type(4))) float f32x4;
typedef __attribute__((ext_vector_type(8))) unsigned short u16x8;

static __device__ __forceinline__ unsigned short f2h_bits(float v) {
    const _Float16 h = (_Float16)v;
    unsigned short b;
    __builtin_memcpy(&b, &h, 2);
    return b;
}
static __device__ __forceinline__ float h2f_u16(unsigned short s) {
    _Float16 h;
    __builtin_memcpy(&h, &s, 2);
    return (float)h;
}
static __device__ __forceinline__ float h2f_lo(unsigned int u) {
    return h2f_u16((unsigned short)(u & 0xffffu));
}
static __device__ __forceinline__ float h2f_hi(unsigned int u) {
    return h2f_u16((unsigned short)(u >> 16));
}

// ---------------- Kernel A: qkv 1x1 conv, 3 sections per block, MFMA hi/lo ----------
// grid (128 pixblocks, B), block 256. X staged+converted ONCE; loop over sections:
// stage W(sec) -> MFMA -> repack acc to LDS f16 -> uint4 stores (16B/lane).
// W LDS region (2*64*72 halfs) is reused as the repack buffer (64*128 halfs).
__global__ void qkv_kernel(const float* __restrict__ x, const float* __restrict__ w,
                           const float* __restrict__ bias,
                           unsigned short* __restrict__ q, unsigned short* __restrict__ k,
                           unsigned short* __restrict__ v) {
    const int pix0 = blockIdx.x * 128;
    const int b    = blockIdx.y;
    const int tid  = threadIdx.x;
    const int lane = tid & 63;
    const int wv   = tid >> 6;

    __shared__ _Float16 xh[128][72], xl[128][72];          // 36864 B
    __shared__ unsigned short wspace[2 * 64 * 72];         // 18432 B (W hi/lo OR repack)
    _Float16* whp = (_Float16*)wspace;                     // [64][72]
    _Float16* wlp = whp + 64 * 72;                         // [64][72]
    unsigned short* rep = wspace;                          // [64][128] (8192 halfs)

    // ---- stage X once ----
    {
        const float* xb = x + (size_t)b * CC * LL + pix0;
        for (int idx = tid; idx < 64 * 128; idx += 256) {
            const int ci = idx >> 7;
            const int px = idx & 127;
            const float vv = xb[(size_t)ci * LL + px];
            const _Float16 h = (_Float16)vv;
            xh[px][ci] = h;
            xl[px][ci] = (_Float16)(vv - (float)h);
        }
    }

    const int g8 = (lane >> 4) * 8;
    const int rl = lane & 15;

    for (int sec = 0; sec < 3; ++sec) {
        __syncthreads();   // X ready (iter 0) / previous section's rep stores done
        // ---- stage W for this section ----
        {
            const float* wsec = w + (size_t)sec * 64 * 64;
            for (int idx = tid; idx < 64 * 64; idx += 256) {
                const int co = idx >> 6;
                const int ci = idx & 63;
                const float vv = wsec[co * 64 + ci];
                const _Float16 h = (_Float16)vv;
                whp[co * 72 + ci] = h;
                wlp[co * 72 + ci] = (_Float16)(vv - (float)h);
            }
        }
        __syncthreads();

        f32x4 acc[4][2];
#pragma unroll
        for (int ct = 0; ct < 4; ++ct)
#pragma unroll
            for (int pt = 0; pt < 2; ++pt) acc[ct][pt] = (f32x4)0.f;

#pragma unroll
        for (int ks = 0; ks < 2; ++ks) {
            const int kb = ks * 32 + g8;
            f16x8 ah[4], al[4], bh[2], bl[2];
#pragma unroll
            for (int ct = 0; ct < 4; ++ct) {
                ah[ct] = *(const f16x8*)&whp[(ct * 16 + rl) * 72 + kb];
                al[ct] = *(const f16x8*)&wlp[(ct * 16 + rl) * 72 + kb];
            }
#pragma unroll
            for (int pt = 0; pt < 2; ++pt) {
                bh[pt] = *(const f16x8*)&xh[wv * 32 + pt * 16 + rl][kb];
                bl[pt] = *(const f16x8*)&xl[wv * 32 + pt * 16 + rl][kb];
            }
#pragma unroll
            for (int ct = 0; ct < 4; ++ct)
#pragma unroll
                for (int pt = 0; pt < 2; ++pt) {
                    acc[ct][pt] = __builtin_amdgcn_mfma_f32_16x16x32_f16(ah[ct], bh[pt], acc[ct][pt], 0, 0, 0);
                    acc[ct][pt] = __builtin_amdgcn_mfma_f32_16x16x32_f16(ah[ct], bl[pt], acc[ct][pt], 0, 0, 0);
                    acc[ct][pt] = __builtin_amdgcn_mfma_f32_16x16x32_f16(al[ct], bh[pt], acc[ct][pt], 0, 0, 0);
                }
        }
        __syncthreads();   // W reads done before rep overwrite

        // ---- repack acc -> rep (f16) with bias (+relu) ----
        const bool do_relu = (sec < 2);
#pragma unroll
        for (int ct = 0; ct < 4; ++ct) {
            const int co_b = ct * 16 + (lane >> 4) * 4;
#pragma unroll
            for (int pt = 0; pt < 2; ++pt) {
                const int pxl = wv * 32 + pt * 16 + rl;
#pragma unroll
                for (int j = 0; j < 4; ++j) {
                    const int co = co_b + j;
                    float val = acc[ct][pt][j] + bias[sec * 64 + co];
                    if (do_relu) val = fmaxf(val, 0.f);
                    rep[co * 128 + pxl] = f2h_bits(val);
                }
            }
        }
        __syncthreads();

        // ---- packed uint4 stores: 1024 slots, 4 per thread ----
        unsigned short* dst = ((sec == 0) ? q : (sec == 1) ? k : v) + (size_t)b * 64 * LL;
#pragma unroll
        for (int i = 0; i < 4; ++i) {
            const int slot = i * 256 + tid;     // 0..1023
            const int co = slot >> 4;
            const int u4 = slot & 15;
            *(uint4*)(dst + (size_t)co * LL + pix0 + u4 * 8) = *(const uint4*)&rep[co * 128 + u4 * 8];
        }
    }
}

// ---------------- Kernel B: KV/KS partials, f16 k/v, pixel-pair lanes ----------
// 32-lane group per k-channel c; 16 lanes (sl) each own col pair (2sl, 2sl+1)
// within 32-col groups; halves own cp 0-3 / 4-7.
__global__ void kv_kernel(const unsigned short* __restrict__ k,
                          const unsigned short* __restrict__ v,
                          float* __restrict__ KVp) {
    const int chunk = blockIdx.x;
    const int h = blockIdx.y;
    const int b = blockIdx.z;
    const int tid = threadIdx.x;
    const int c  = tid >> 5;
    const int s  = tid & 31;
    const int half = s >> 4;
    const int sl   = s & 15;
    const int cpb  = half * 4;

    __shared__ float klds[8][6][130];

    {
        const unsigned short* kb = k + ((size_t)(b * 64) + 8 * h) * LL;
        for (int t = tid; t < 8 * 6 * 130; t += 256) {
            const int ch = t / 780;
            const int r1 = t - ch * 780;
            const int lr = r1 / 130;
            const int cx = r1 - lr * 130;
            const int gy = chunk * 4 + lr - 1;
            const int gx = cx - 1;
            const bool ok = (gy >= 0 && gy < HH && gx >= 0 && gx < WW);
            klds[ch][lr][cx] = ok ? h2f_u16(kb[(size_t)ch * LL + gy * WW + gx]) : 0.f;
        }
    }
    __syncthreads();

    const unsigned short* vbase = v + ((size_t)(b * 64) + 8 * h + cpb) * LL;

    float kv4[9][4] = {{0.f}};
    float ks[9] = {0.f};

    for (int r = 0; r < 4; ++r) {
        const int y = chunk * 4 + r;
        for (int g = 0; g < 4; ++g) {
            const int col0 = g * 32 + sl * 2;
            float va[4], vb2[4];
#pragma unroll
            for (int cp = 0; cp < 4; ++cp) {
                const unsigned int u = *(const unsigned int*)(vbase + (size_t)cp * LL + y * WW + col0);
                va[cp]  = h2f_lo(u);
                vb2[cp] = h2f_hi(u);
            }
            float kw[3][4];
#pragma unroll
            for (int dy = 0; dy < 3; ++dy)
#pragma unroll
                for (int dxx = 0; dxx < 4; ++dxx)
                    kw[dy][dxx] = klds[c][r + dy][col0 + dxx];
#pragma unroll
            for (int dy = 0; dy < 3; ++dy)
#pragma unroll
                for (int dx = 0; dx < 3; ++dx) {
                    const int p = dy * 3 + dx;
                    const float ka  = kw[dy][dx];
                    const float kb2 = kw[dy][dx + 1];
                    ks[p] += ka + kb2;
#pragma unroll
                    for (int cp = 0; cp < 4; ++cp)
                        kv4[p][cp] = fmaf(kb2, vb2[cp], fmaf(ka, va[cp], kv4[p][cp]));
                }
        }
    }

#pragma unroll
    for (int p = 0; p < 9; ++p) {
#pragma unroll
        for (int m = 8; m >= 1; m >>= 1) ks[p] += __shfl_xor(ks[p], m);
#pragma unroll
        for (int cp = 0; cp < 4; ++cp) {
#pragma unroll
            for (int m = 8; m >= 1; m >>= 1) kv4[p][cp] += __shfl_xor(kv4[p][cp], m);
        }
    }

    if (sl == 0) {
        float* dst = KVp + (((size_t)(b * NH + h) * KVCHUNKS) + chunk) * 648;
#pragma unroll
        for (int p = 0; p < 9; ++p) {
#pragma unroll
            for (int cp = 0; cp < 4; ++cp)
                dst[(c * 9 + p) * 8 + cpb + cp] = kv4[p][cp];
            if (half == 0) dst[576 + c * 9 + p] = ks[p];
        }
    }
}

// ---------------- Kernel B2: reduce 32 chunk-partials -> KV, KS ----------------
__global__ void kv_finalize(const float* __restrict__ KVp,
                            float* __restrict__ KV, float* __restrict__ KS) {
    const int bh = blockIdx.x;
    const float* src = KVp + (size_t)bh * KVCHUNKS * 648;
    for (int idx = threadIdx.x; idx < 648; idx += 256) {
        float s0 = 0.f, s1 = 0.f, s2 = 0.f, s3 = 0.f;
#pragma unroll
        for (int ch = 0; ch < KVCHUNKS; ch += 4) {
            s0 += src[(ch + 0) * 648 + idx];
            s1 += src[(ch + 1) * 648 + idx];
            s2 += src[(ch + 2) * 648 + idx];
            s3 += src[(ch + 3) * 648 + idx];
        }
        const float sum = (s0 + s1) + (s2 + s3);
        if (idx < 576) KV[(size_t)bh * 576 + idx] = sum;
        else           KS[(size_t)bh * 72 + (idx - 576)] = sum;
    }
}

// ---------------- Kernel C: attn, pixel-pair per thread, uint transport ----------
__global__ void attn_kernel(const unsigned short* __restrict__ q, const float* __restrict__ KV,
                            const float* __restrict__ KS, unsigned int* __restrict__ aofu) {
    const int y = blockIdx.x;
    const int h = blockIdx.y;
    const int b = blockIdx.z;
    const int t = threadIdx.x;   // 0..63

    float out0[8] = {0.f}, out1[8] = {0.f};
    float den0 = 0.f, den1 = 0.f;
    const int kvbase = (b * NH + h) * 8;
    const bool tlo = (t > 0), thi = (t < 63);

    for (int c = 0; c < 8; ++c) {
        const unsigned short* qc = q + ((size_t)(b * 64) + 8 * h + c) * LL;
        float qw[3][6];
#pragma unroll
        for (int dy = 0; dy < 3; ++dy) {
            const int yy = y + dy - 1;
            const bool yok = (yy >= 0 && yy < HH);
            const unsigned short* row = qc + yy * WW;
            const unsigned int u0 = (yok && tlo) ? *(const unsigned int*)(row + 2 * t - 2) : 0u;
            const unsigned int u1 = yok ? *(const unsigned int*)(row + 2 * t) : 0u;
            const unsigned int u2 = (yok && thi) ? *(const unsigned int*)(row + 2 * t + 2) : 0u;
            qw[dy][0] = h2f_lo(u0);  qw[dy][1] = h2f_hi(u0);
            qw[dy][2] = h2f_lo(u1);  qw[dy][3] = h2f_hi(u1);
            qw[dy][4] = h2f_lo(u2);  qw[dy][5] = h2f_hi(u2);
        }
        const float* kvr = KV + ((size_t)(kvbase + c) * 9) * 8;  // wave-uniform
        const float* ksr = KS + (size_t)(kvbase + c) * 9;
#pragma unroll
        for (int dy = 0; dy < 3; ++dy)
#pragma unroll
            for (int dx = 0; dx < 3; ++dx) {
                const int p = dy * 3 + dx;
                const float q0 = qw[dy][1 + dx];
                const float q1 = qw[dy][2 + dx];
                const float ksv = ksr[p];
                den0 = fmaf(q0, ksv, den0);
                den1 = fmaf(q1, ksv, den1);
#pragma unroll
                for (int cp = 0; cp < 8; ++cp) {
                    const float kvv = kvr[p * 8 + cp];
                    out0[cp] = fmaf(q0, kvv, out0[cp]);
                    out1[cp] = fmaf(q1, kvv, out1[cp]);
                }
            }
    }
    const float inv0 = 1.f / (den0 + EPSF);
    const float inv1 = 1.f / (den1 + EPSF);
    const int pixu = y * (WW / 2) + t;
#pragma unroll
    for (int cp = 0; cp < 8; ++cp) {
        const unsigned int lo = f2h_bits(out0[cp] * inv0);
        const unsigned int hi = f2h_bits(out1[cp] * inv1);
        aofu[((size_t)(b * 64) + h * 8 + cp) * (LL / 2) + pixu] = lo | (hi << 16);
    }
}

// ---------------- Kernel W: pre-split proj_w into MFMA fragment layout (single f16) --
__global__ void wprep_kernel(const float* __restrict__ w, unsigned short* __restrict__ wfrag) {
    const int idx = blockIdx.x * 256 + threadIdx.x;   // 16*64*64 = 65536
    const int k  = idx & 63;
    const int co = (idx >> 6) & 63;
    const int ks = idx >> 12;
    const int kg = ks * 64 + k;
    const int ci = kg >> 4, tap = kg & 15;
    const float vv = (tap < 9) ? w[(co * 64 + ci) * 9 + tap] : 0.f;
    const int kx = (((k >> 3) ^ (co & 7)) << 3) | (k & 7);
    wfrag[((size_t)ks * 64 + co) * 64 + kx] = f2h_bits(vv);
}

// ---------------- Kernel D: 3x3 conv via MFMA; all-f16 operands; dbuf LDS ----------
#define CONV_PREFETCH(KS)                                                        \
    do {                                                                         \
        const unsigned short* src_ = aofb + (size_t)((KS) * 4 + scis) * LL;      \
        pf0 = (oky0 && okxm) ? src_[offm - WW] : (unsigned short)0;              \
        pf1 = oky0 ? src_[off0 - WW] : (unsigned short)0;                        \
        pf2 = (oky0 && okxp) ? src_[offp - WW] : (unsigned short)0;              \
        pf3 = okxm ? src_[offm] : (unsigned short)0;                             \
        pf4 = src_[off0];                                                        \
        pf5 = okxp ? src_[offp] : (unsigned short)0;                             \
        pf6 = (oky2 && okxm) ? src_[offm + WW] : (unsigned short)0;              \
        pf7 = oky2 ? src_[off0 + WW] : (unsigned short)0;                        \
        pf8 = (oky2 && okxp) ? src_[offp + WW] : (unsigned short)0;              \
        const uint4* wsrc_ = (const uint4*)(wfrag + (size_t)(KS) * 4096);        \
        wf0 = wsrc_[tid];                                                        \
        wf1 = wsrc_[256 + tid];                                                  \
    } while (0)

__global__ __launch_bounds__(256) void conv_kernel(const unsigned short* __restrict__ aof,
                                                   const unsigned short* __restrict__ wfrag,
                                                   const float* __restrict__ bias,
                                                   float* __restrict__ out) {
    const int bid = blockIdx.x;
    const int swz = (bid & 7) * 128 + (bid >> 3);   // XCD-chunked
    const int b = swz >> 8;
    const int rem = swz & 255;
    const int y = rem >> 1;
    const int colbase = (rem & 1) * 64;
    const int tid = threadIdx.x;
    const int lane = tid & 63;
    const int wv = tid >> 6;
    const int rl = lane & 15;
    const int g  = lane >> 4;

    __shared__ unsigned short plds[2][64 * 64];   // 2 x 8192 B (P single f16)
    __shared__ unsigned short wlds[2][64 * 64];   // 2 x 8192 B (W single f16)

    f32x4 acc[4];
#pragma unroll
    for (int ct = 0; ct < 4; ++ct) acc[ct] = (f32x4)0.f;

    const int spix = tid & 63;
    const int scis = tid >> 6;

    const unsigned short* aofb = aof + (size_t)b * 64 * LL;
    const int xc   = colbase + spix;
    const int off0 = y * WW + xc;
    const int offm = off0 - 1;
    const int offp = off0 + 1;
    const bool oky0 = (y > 0);
    const bool oky2 = (y < HH - 1);
    const bool okxm = (xc > 0);
    const bool okxp = (xc < WW - 1);
    const int xs0 = (((2 * scis)     ^ (spix & 7)) << 3);
    const int xs1 = (((2 * scis + 1) ^ (spix & 7)) << 3);

    unsigned short pf0, pf1, pf2, pf3, pf4, pf5, pf6, pf7, pf8;
    uint4 wf0, wf1;

    CONV_PREFETCH(0);

    for (int ks = 0; ks < 16; ++ks) {
        const int cur = ks & 1;
        {
            unsigned short h16[16];
            h16[0] = pf0;  h16[1] = pf1;  h16[2] = pf2;
            h16[3] = pf3;  h16[4] = pf4;  h16[5] = pf5;
            h16[6] = pf6;  h16[7] = pf7;  h16[8] = pf8;
#pragma unroll
            for (int j = 9; j < 16; ++j) h16[j] = 0;
            *(u16x8*)&plds[cur][spix * 64 + xs0] = *(u16x8*)&h16[0];
            *(u16x8*)&plds[cur][spix * 64 + xs1] = *(u16x8*)&h16[8];
            uint4* wdst = (uint4*)&wlds[cur][0];
            wdst[tid]       = wf0;
            wdst[256 + tid] = wf1;
        }
        __syncthreads();
        if (ks < 15) CONV_PREFETCH(ks + 1);

#pragma unroll
        for (int ksub = 0; ksub < 2; ++ksub) {
            const int xs = (((ksub * 4 + g) ^ (rl & 7)) << 3);
            const int row = wv * 16 + rl;
            const f16x8 bh = *(const f16x8*)&plds[cur][row * 64 + xs];
#pragma unroll
            for (int ct = 0; ct < 4; ++ct) {
                const int rowa = ct * 16 + rl;
                const f16x8 ah = *(const f16x8*)&wlds[cur][rowa * 64 + xs];
                acc[ct] = __builtin_amdgcn_mfma_f32_16x16x32_f16(ah, bh, acc[ct], 0, 0, 0);
            }
        }
    }

#pragma unroll
    for (int ct = 0; ct < 4; ++ct) {
        const int co_b = ct * 16 + g * 4;
        const int px = colbase + wv * 16 + rl;
#pragma unroll
        for (int j = 0; j < 4; ++j) {
            const int co = co_b + j;
            out[((size_t)b * 64 + co) * LL + y * WW + px] = acc[ct][j] + bias[co];
        }
    }
}

extern "C" void kernel_launch(void* const* d_in, const int* in_sizes, int n_in,
                              void* d_out, int out_size, void* d_ws, size_t ws_size,
                              hipStream_t stream) {
    const float* x      = (const float*)d_in[0];
    const float* qkv_w  = (const float*)d_in[1];
    const float* qkv_b  = (const float*)d_in[2];
    const float* proj_w = (const float*)d_in[3];
    const float* proj_b = (const float*)d_in[4];
    float* out = (float*)d_out;
    float* ws  = (float*)d_ws;

    const size_t n1 = (size_t)4 * 64 * LL;      // one B*C*L fp32 plane set
    unsigned short* qb  = (unsigned short*)ws;            // f16
    unsigned short* kb  = (unsigned short*)(ws + n1);     // f16
    unsigned short* vb  = (unsigned short*)(ws + 2 * n1); // f16
    unsigned short* aof = (unsigned short*)(ws + 3 * n1); // f16
    float* KV   = ws + 4 * n1;                  // 4*8*8*9*8 = 18432 floats
    float* KS   = KV + 4 * 8 * 8 * 9 * 8;       // 4*8*8*9  = 2304 floats
    float* KVp  = KS + 4 * 8 * 8 * 9;           // 32*32*648 = 663552 floats
    unsigned short* wfrag = (unsigned short*)(KVp + (size_t)32 * KVCHUNKS * 648);  // 65536 halfs

    wprep_kernel<<<256, 256, 0, stream>>>(proj_w, wfrag);
    qkv_kernel<<<dim3(128, 4), 256, 0, stream>>>(x, qkv_w, qkv_b, qb, kb, vb);
    kv_kernel<<<dim3(KVCHUNKS, NH, 4), 256, 0, stream>>>(kb, vb, KVp);
    kv_finalize<<<32, 256, 0, stream>>>(KVp, KV, KS);
    attn_kernel<<<dim3(128, NH, 4), 64, 0, stream>>>(qb, KV, KS, (unsigned int*)aof);
    conv_kernel<<<1024, 256, 0, stream>>>(aof, wfrag, proj_b, out);
}

// Round 22
// 96.965 us; speedup vs baseline: 1.3306x; 1.0400x over previous
//
#include <hip/hip_runtime.h>
#include <hip/hip_fp16.h>

#define LL 16384
#define HH 128
#define WW 128
#define CC 64
#define NH 8
#define EPSF 1e-7f
#define KVCHUNKS 32

typedef __attribute__((ext_vector_type(8))) _Float16 f16x8;
typedef __attribute__((ext_vector_type(4))) float f32x4;
typedef __attribute__((ext_vector_type(8))) unsigned short u16x8;

static __device__ __forceinline__ unsigned short f2h_bits(float v) {
    const _Float16 h = (_Float16)v;
    unsigned short b;
    __builtin_memcpy(&b, &h, 2);
    return b;
}
static __device__ __forceinline__ float h2f_u16(unsigned short s) {
    _Float16 h;
    __builtin_memcpy(&h, &s, 2);
    return (float)h;
}
static __device__ __forceinline__ float h2f_lo(unsigned int u) {
    return h2f_u16((unsigned short)(u & 0xffffu));
}
static __device__ __forceinline__ float h2f_hi(unsigned int u) {
    return h2f_u16((unsigned short)(u >> 16));
}

// ---------------- Kernel A: qkv 1x1 conv, 3 sections per block, MFMA hi/lo ----------
__global__ void qkv_kernel(const float* __restrict__ x, const float* __restrict__ w,
                           const float* __restrict__ bias,
                           unsigned short* __restrict__ q, unsigned short* __restrict__ k,
                           unsigned short* __restrict__ v) {
    const int pix0 = blockIdx.x * 128;
    const int b    = blockIdx.y;
    const int tid  = threadIdx.x;
    const int lane = tid & 63;
    const int wv   = tid >> 6;

    __shared__ _Float16 xh[128][72], xl[128][72];          // 36864 B
    __shared__ unsigned short wspace[2 * 64 * 72];         // 18432 B (W hi/lo OR repack)
    _Float16* whp = (_Float16*)wspace;                     // [64][72]
    _Float16* wlp = whp + 64 * 72;                         // [64][72]
    unsigned short* rep = wspace;                          // [64][128]

    {
        const float* xb = x + (size_t)b * CC * LL + pix0;
        for (int idx = tid; idx < 64 * 128; idx += 256) {
            const int ci = idx >> 7;
            const int px = idx & 127;
            const float vv = xb[(size_t)ci * LL + px];
            const _Float16 h = (_Float16)vv;
            xh[px][ci] = h;
            xl[px][ci] = (_Float16)(vv - (float)h);
        }
    }

    const int g8 = (lane >> 4) * 8;
    const int rl = lane & 15;

    for (int sec = 0; sec < 3; ++sec) {
        __syncthreads();
        {
            const float* wsec = w + (size_t)sec * 64 * 64;
            for (int idx = tid; idx < 64 * 64; idx += 256) {
                const int co = idx >> 6;
                const int ci = idx & 63;
                const float vv = wsec[co * 64 + ci];
                const _Float16 h = (_Float16)vv;
                whp[co * 72 + ci] = h;
                wlp[co * 72 + ci] = (_Float16)(vv - (float)h);
            }
        }
        __syncthreads();

        f32x4 acc[4][2];
#pragma unroll
        for (int ct = 0; ct < 4; ++ct)
#pragma unroll
            for (int pt = 0; pt < 2; ++pt) acc[ct][pt] = (f32x4)0.f;

#pragma unroll
        for (int ks = 0; ks < 2; ++ks) {
            const int kb = ks * 32 + g8;
            f16x8 ah[4], al[4], bh[2], bl[2];
#pragma unroll
            for (int ct = 0; ct < 4; ++ct) {
                ah[ct] = *(const f16x8*)&whp[(ct * 16 + rl) * 72 + kb];
                al[ct] = *(const f16x8*)&wlp[(ct * 16 + rl) * 72 + kb];
            }
#pragma unroll
            for (int pt = 0; pt < 2; ++pt) {
                bh[pt] = *(const f16x8*)&xh[wv * 32 + pt * 16 + rl][kb];
                bl[pt] = *(const f16x8*)&xl[wv * 32 + pt * 16 + rl][kb];
            }
#pragma unroll
            for (int ct = 0; ct < 4; ++ct)
#pragma unroll
                for (int pt = 0; pt < 2; ++pt) {
                    acc[ct][pt] = __builtin_amdgcn_mfma_f32_16x16x32_f16(ah[ct], bh[pt], acc[ct][pt], 0, 0, 0);
                    acc[ct][pt] = __builtin_amdgcn_mfma_f32_16x16x32_f16(ah[ct], bl[pt], acc[ct][pt], 0, 0, 0);
                    acc[ct][pt] = __builtin_amdgcn_mfma_f32_16x16x32_f16(al[ct], bh[pt], acc[ct][pt], 0, 0, 0);
                }
        }
        __syncthreads();

        const bool do_relu = (sec < 2);
#pragma unroll
        for (int ct = 0; ct < 4; ++ct) {
            const int co_b = ct * 16 + (lane >> 4) * 4;
#pragma unroll
            for (int pt = 0; pt < 2; ++pt) {
                const int pxl = wv * 32 + pt * 16 + rl;
#pragma unroll
                for (int j = 0; j < 4; ++j) {
                    const int co = co_b + j;
                    float val = acc[ct][pt][j] + bias[sec * 64 + co];
                    if (do_relu) val = fmaxf(val, 0.f);
                    rep[co * 128 + pxl] = f2h_bits(val);
                }
            }
        }
        __syncthreads();

        unsigned short* dst = ((sec == 0) ? q : (sec == 1) ? k : v) + (size_t)b * 64 * LL;
#pragma unroll
        for (int i = 0; i < 4; ++i) {
            const int slot = i * 256 + tid;
            const int co = slot >> 4;
            const int u4 = slot & 15;
            *(uint4*)(dst + (size_t)co * LL + pix0 + u4 * 8) = *(const uint4*)&rep[co * 128 + u4 * 8];
        }
    }
}

// ---------------- Kernel B: KV/KS partials, f16 k/v, pixel-pair lanes ----------
__global__ void kv_kernel(const unsigned short* __restrict__ k,
                          const unsigned short* __restrict__ v,
                          float* __restrict__ KVp) {
    const int chunk = blockIdx.x;
    const int h = blockIdx.y;
    const int b = blockIdx.z;
    const int tid = threadIdx.x;
    const int c  = tid >> 5;
    const int s  = tid & 31;
    const int half = s >> 4;
    const int sl   = s & 15;
    const int cpb  = half * 4;

    __shared__ float klds[8][6][130];

    {
        const unsigned short* kb = k + ((size_t)(b * 64) + 8 * h) * LL;
        for (int t = tid; t < 8 * 6 * 130; t += 256) {
            const int ch = t / 780;
            const int r1 = t - ch * 780;
            const int lr = r1 / 130;
            const int cx = r1 - lr * 130;
            const int gy = chunk * 4 + lr - 1;
            const int gx = cx - 1;
            const bool ok = (gy >= 0 && gy < HH && gx >= 0 && gx < WW);
            klds[ch][lr][cx] = ok ? h2f_u16(kb[(size_t)ch * LL + gy * WW + gx]) : 0.f;
        }
    }
    __syncthreads();

    const unsigned short* vbase = v + ((size_t)(b * 64) + 8 * h + cpb) * LL;

    float kv4[9][4] = {{0.f}};
    float ks[9] = {0.f};

    for (int r = 0; r < 4; ++r) {
        const int y = chunk * 4 + r;
        for (int g = 0; g < 4; ++g) {
            const int col0 = g * 32 + sl * 2;
            float va[4], vb2[4];
#pragma unroll
            for (int cp = 0; cp < 4; ++cp) {
                const unsigned int u = *(const unsigned int*)(vbase + (size_t)cp * LL + y * WW + col0);
                va[cp]  = h2f_lo(u);
                vb2[cp] = h2f_hi(u);
            }
            float kw[3][4];
#pragma unroll
            for (int dy = 0; dy < 3; ++dy)
#pragma unroll
                for (int dxx = 0; dxx < 4; ++dxx)
                    kw[dy][dxx] = klds[c][r + dy][col0 + dxx];
#pragma unroll
            for (int dy = 0; dy < 3; ++dy)
#pragma unroll
                for (int dx = 0; dx < 3; ++dx) {
                    const int p = dy * 3 + dx;
                    const float ka  = kw[dy][dx];
                    const float kb2 = kw[dy][dx + 1];
                    ks[p] += ka + kb2;
#pragma unroll
                    for (int cp = 0; cp < 4; ++cp)
                        kv4[p][cp] = fmaf(kb2, vb2[cp], fmaf(ka, va[cp], kv4[p][cp]));
                }
        }
    }

#pragma unroll
    for (int p = 0; p < 9; ++p) {
#pragma unroll
        for (int m = 8; m >= 1; m >>= 1) ks[p] += __shfl_xor(ks[p], m);
#pragma unroll
        for (int cp = 0; cp < 4; ++cp) {
#pragma unroll
            for (int m = 8; m >= 1; m >>= 1) kv4[p][cp] += __shfl_xor(kv4[p][cp], m);
        }
    }

    if (sl == 0) {
        float* dst = KVp + (((size_t)(b * NH + h) * KVCHUNKS) + chunk) * 648;
#pragma unroll
        for (int p = 0; p < 9; ++p) {
#pragma unroll
            for (int cp = 0; cp < 4; ++cp)
                dst[(c * 9 + p) * 8 + cpb + cp] = kv4[p][cp];
            if (half == 0) dst[576 + c * 9 + p] = ks[p];
        }
    }
}

// ---------------- Kernel B2+W merged: finalize KV/KS (blocks 0-31) + wprep (32-287) --
__global__ void prep_kernel(const float* __restrict__ KVp,
                            float* __restrict__ KV, float* __restrict__ KS,
                            const float* __restrict__ w, unsigned short* __restrict__ wfrag) {
    if (blockIdx.x < 32) {
        const int bh = blockIdx.x;
        const float* src = KVp + (size_t)bh * KVCHUNKS * 648;
        for (int idx = threadIdx.x; idx < 648; idx += 256) {
            float s0 = 0.f, s1 = 0.f, s2 = 0.f, s3 = 0.f;
#pragma unroll
            for (int ch = 0; ch < KVCHUNKS; ch += 4) {
                s0 += src[(ch + 0) * 648 + idx];
                s1 += src[(ch + 1) * 648 + idx];
                s2 += src[(ch + 2) * 648 + idx];
                s3 += src[(ch + 3) * 648 + idx];
            }
            const float sum = (s0 + s1) + (s2 + s3);
            if (idx < 576) KV[(size_t)bh * 576 + idx] = sum;
            else           KS[(size_t)bh * 72 + (idx - 576)] = sum;
        }
    } else {
        const int idx = (blockIdx.x - 32) * 256 + threadIdx.x;   // 0..65535
        const int kk = idx & 63;
        const int co = (idx >> 6) & 63;
        const int ks = idx >> 12;
        const int kg = ks * 64 + kk;
        const int ci = kg >> 4, tap = kg & 15;
        const float vv = (tap < 9) ? w[(co * 64 + ci) * 9 + tap] : 0.f;
        const int kx = (((kk >> 3) ^ (co & 7)) << 3) | (kk & 7);
        wfrag[((size_t)ks * 64 + co) * 64 + kx] = f2h_bits(vv);
    }
}

// ---------------- Kernel C: attn, pixel-pair per thread, uint transport ----------
__global__ void attn_kernel(const unsigned short* __restrict__ q, const float* __restrict__ KV,
                            const float* __restrict__ KS, unsigned int* __restrict__ aofu) {
    const int y = blockIdx.x;
    const int h = blockIdx.y;
    const int b = blockIdx.z;
    const int t = threadIdx.x;   // 0..63

    float out0[8] = {0.f}, out1[8] = {0.f};
    float den0 = 0.f, den1 = 0.f;
    const int kvbase = (b * NH + h) * 8;
    const bool tlo = (t > 0), thi = (t < 63);

    for (int c = 0; c < 8; ++c) {
        const unsigned short* qc = q + ((size_t)(b * 64) + 8 * h + c) * LL;
        float qw[3][6];
#pragma unroll
        for (int dy = 0; dy < 3; ++dy) {
            const int yy = y + dy - 1;
            const bool yok = (yy >= 0 && yy < HH);
            const unsigned short* row = qc + yy * WW;
            const unsigned int u0 = (yok && tlo) ? *(const unsigned int*)(row + 2 * t - 2) : 0u;
            const unsigned int u1 = yok ? *(const unsigned int*)(row + 2 * t) : 0u;
            const unsigned int u2 = (yok && thi) ? *(const unsigned int*)(row + 2 * t + 2) : 0u;
            qw[dy][0] = h2f_lo(u0);  qw[dy][1] = h2f_hi(u0);
            qw[dy][2] = h2f_lo(u1);  qw[dy][3] = h2f_hi(u1);
            qw[dy][4] = h2f_lo(u2);  qw[dy][5] = h2f_hi(u2);
        }
        const float* kvr = KV + ((size_t)(kvbase + c) * 9) * 8;  // wave-uniform
        const float* ksr = KS + (size_t)(kvbase + c) * 9;
#pragma unroll
        for (int dy = 0; dy < 3; ++dy)
#pragma unroll
            for (int dx = 0; dx < 3; ++dx) {
                const int p = dy * 3 + dx;
                const float q0 = qw[dy][1 + dx];
                const float q1 = qw[dy][2 + dx];
                const float ksv = ksr[p];
                den0 = fmaf(q0, ksv, den0);
                den1 = fmaf(q1, ksv, den1);
#pragma unroll
                for (int cp = 0; cp < 8; ++cp) {
                    const float kvv = kvr[p * 8 + cp];
                    out0[cp] = fmaf(q0, kvv, out0[cp]);
                    out1[cp] = fmaf(q1, kvv, out1[cp]);
                }
            }
    }
    const float inv0 = 1.f / (den0 + EPSF);
    const float inv1 = 1.f / (den1 + EPSF);
    const int pixu = y * (WW / 2) + t;
#pragma unroll
    for (int cp = 0; cp < 8; ++cp) {
        const unsigned int lo = f2h_bits(out0[cp] * inv0);
        const unsigned int hi = f2h_bits(out1[cp] * inv1);
        aofu[((size_t)(b * 64) + h * 8 + cp) * (LL / 2) + pixu] = lo | (hi << 16);
    }
}

// ---------------- Kernel D: 3x3 conv via MFMA; pair-staged P (uint loads) ----------
// grid 1024 (XCD-chunk swizzled), block 256 = 4 waves.
// Staging split: threads 0-127 (waves 0-1) stage P: pixel PAIR x 1 ci via 9 aligned
// uint loads (shared 3x3 windows); threads 128-255 (waves 2-3) stage W: 4 uint4 each.
// All 256 threads run the MFMA phase. Values bit-identical to R21.
#define CONV_PREFETCH(KS)                                                        \
    do {                                                                         \
        if (tid < 128) {                                                         \
            const unsigned short* src_ = aofb + (size_t)((KS) * 4 + scis) * LL;  \
            pa0 = (oky0 && u0ok) ? *(const unsigned int*)(src_ + o_m - 2) : 0u;  \
            pa1 = oky0 ? *(const unsigned int*)(src_ + o_m) : 0u;                \
            pa2 = (oky0 && u2ok) ? *(const unsigned int*)(src_ + o_m + 2) : 0u;  \
            pb0 = u0ok ? *(const unsigned int*)(src_ + o_c - 2) : 0u;            \
            pb1 = *(const unsigned int*)(src_ + o_c);                            \
            pb2 = u2ok ? *(const unsigned int*)(src_ + o_c + 2) : 0u;            \
            pc0 = (oky2 && u0ok) ? *(const unsigned int*)(src_ + o_p - 2) : 0u;  \
            pc1 = oky2 ? *(const unsigned int*)(src_ + o_p) : 0u;                \
            pc2 = (oky2 && u2ok) ? *(const unsigned int*)(src_ + o_p + 2) : 0u;  \
        } else {                                                                 \
            const uint4* wsrc_ = (const uint4*)(wfrag + (size_t)(KS) * 4096);    \
            wf0 = wsrc_[wt];        wf1 = wsrc_[128 + wt];                       \
            wf2 = wsrc_[256 + wt];  wf3 = wsrc_[384 + wt];                       \
        }                                                                        \
    } while (0)

__global__ __launch_bounds__(256) void conv_kernel(const unsigned short* __restrict__ aof,
                                                   const unsigned short* __restrict__ wfrag,
                                                   const float* __restrict__ bias,
                                                   float* __restrict__ out) {
    const int bid = blockIdx.x;
    const int swz = (bid & 7) * 128 + (bid >> 3);   // XCD-chunked
    const int b = swz >> 8;
    const int rem = swz & 255;
    const int y = rem >> 1;
    const int colbase = (rem & 1) * 64;
    const int tid = threadIdx.x;
    const int lane = tid & 63;
    const int wv = tid >> 6;
    const int rl = lane & 15;
    const int g  = lane >> 4;

    __shared__ unsigned short plds[2][64 * 64];   // 2 x 8192 B (P single f16)
    __shared__ unsigned short wlds[2][64 * 64];   // 2 x 8192 B (W single f16)

    f32x4 acc[4];
#pragma unroll
    for (int ct = 0; ct < 4; ++ct) acc[ct] = (f32x4)0.f;

    // staging roles
    const int pair = tid & 31;           // P threads: pair index
    const int scis = (tid >> 5) & 3;     // P threads: ci select
    const int wt   = tid & 127;          // W threads: slot base
    const int pxA  = pair * 2;           // local pixel A (even)
    const int pxB  = pxA + 1;

    const unsigned short* aofb = aof + (size_t)b * 64 * LL;
    const int xc0 = colbase + pxA;
    const int o_c = y * WW + xc0;
    const int o_m = o_c - WW;
    const int o_p = o_c + WW;
    const bool oky0 = (y > 0);
    const bool oky2 = (y < HH - 1);
    const bool u0ok = (xc0 >= 2);
    const bool u2ok = (xc0 + 3 < WW);
    const int xsA0 = (((2 * scis)     ^ (pxA & 7)) << 3);
    const int xsA1 = (((2 * scis + 1) ^ (pxA & 7)) << 3);
    const int xsB0 = (((2 * scis)     ^ (pxB & 7)) << 3);
    const int xsB1 = (((2 * scis + 1) ^ (pxB & 7)) << 3);

    unsigned int pa0, pa1, pa2, pb0, pb1, pb2, pc0, pc1, pc2;
    uint4 wf0, wf1, wf2, wf3;

    CONV_PREFETCH(0);

    for (int ks = 0; ks < 16; ++ks) {
        const int cur = ks & 1;
        if (tid < 128) {
            // pixel A window: [hi(u0), lo(u1), hi(u1)] per row
            unsigned short ha[16], hb[16];
            ha[0] = (unsigned short)(pa0 >> 16);      ha[1] = (unsigned short)(pa1 & 0xffffu);  ha[2] = (unsigned short)(pa1 >> 16);
            ha[3] = (unsigned short)(pb0 >> 16);      ha[4] = (unsigned short)(pb1 & 0xffffu);  ha[5] = (unsigned short)(pb1 >> 16);
            ha[6] = (unsigned short)(pc0 >> 16);      ha[7] = (unsigned short)(pc1 & 0xffffu);  ha[8] = (unsigned short)(pc1 >> 16);
            // pixel B window: [lo(u1), hi(u1), lo(u2)] per row
            hb[0] = (unsigned short)(pa1 & 0xffffu);  hb[1] = (unsigned short)(pa1 >> 16);      hb[2] = (unsigned short)(pa2 & 0xffffu);
            hb[3] = (unsigned short)(pb1 & 0xffffu);  hb[4] = (unsigned short)(pb1 >> 16);      hb[5] = (unsigned short)(pb2 & 0xffffu);
            hb[6] = (unsigned short)(pc1 & 0xffffu);  hb[7] = (unsigned short)(pc1 >> 16);      hb[8] = (unsigned short)(pc2 & 0xffffu);
#pragma unroll
            for (int j = 9; j < 16; ++j) { ha[j] = 0; hb[j] = 0; }
            *(u16x8*)&plds[cur][pxA * 64 + xsA0] = *(u16x8*)&ha[0];
            *(u16x8*)&plds[cur][pxA * 64 + xsA1] = *(u16x8*)&ha[8];
            *(u16x8*)&plds[cur][pxB * 64 + xsB0] = *(u16x8*)&hb[0];
            *(u16x8*)&plds[cur][pxB * 64 + xsB1] = *(u16x8*)&hb[8];
        } else {
            uint4* wdst = (uint4*)&wlds[cur][0];
            wdst[wt]        = wf0;
            wdst[128 + wt]  = wf1;
            wdst[256 + wt]  = wf2;
            wdst[384 + wt]  = wf3;
        }
        __syncthreads();
        if (ks < 15) CONV_PREFETCH(ks + 1);

#pragma unroll
        for (int ksub = 0; ksub < 2; ++ksub) {
            const int xs = (((ksub * 4 + g) ^ (rl & 7)) << 3);
            const int row = wv * 16 + rl;
            const f16x8 bh = *(const f16x8*)&plds[cur][row * 64 + xs];
#pragma unroll
            for (int ct = 0; ct < 4; ++ct) {
                const int rowa = ct * 16 + rl;
                const f16x8 ah = *(const f16x8*)&wlds[cur][rowa * 64 + xs];
                acc[ct] = __builtin_amdgcn_mfma_f32_16x16x32_f16(ah, bh, acc[ct], 0, 0, 0);
            }
        }
    }

#pragma unroll
    for (int ct = 0; ct < 4; ++ct) {
        const int co_b = ct * 16 + g * 4;
        const int px = colbase + wv * 16 + rl;
#pragma unroll
        for (int j = 0; j < 4; ++j) {
            const int co = co_b + j;
            out[((size_t)b * 64 + co) * LL + y * WW + px] = acc[ct][j] + bias[co];
        }
    }
}

extern "C" void kernel_launch(void* const* d_in, const int* in_sizes, int n_in,
                              void* d_out, int out_size, void* d_ws, size_t ws_size,
                              hipStream_t stream) {
    const float* x      = (const float*)d_in[0];
    const float* qkv_w  = (const float*)d_in[1];
    const float* qkv_b  = (const float*)d_in[2];
    const float* proj_w = (const float*)d_in[3];
    const float* proj_b = (const float*)d_in[4];
    float* out = (float*)d_out;
    float* ws  = (float*)d_ws;

    const size_t n1 = (size_t)4 * 64 * LL;      // one B*C*L fp32 plane set
    unsigned short* qb  = (unsigned short*)ws;            // f16
    unsigned short* kb  = (unsigned short*)(ws + n1);     // f16
    unsigned short* vb  = (unsigned short*)(ws + 2 * n1); // f16
    unsigned short* aof = (unsigned short*)(ws + 3 * n1); // f16
    float* KV   = ws + 4 * n1;                  // 4*8*8*9*8 = 18432 floats
    float* KS   = KV + 4 * 8 * 8 * 9 * 8;       // 4*8*8*9  = 2304 floats
    float* KVp  = KS + 4 * 8 * 8 * 9;           // 32*32*648 = 663552 floats
    unsigned short* wfrag = (unsigned short*)(KVp + (size_t)32 * KVCHUNKS * 648);  // 65536 halfs

    qkv_kernel<<<dim3(128, 4), 256, 0, stream>>>(x, qkv_w, qkv_b, qb, kb, vb);
    kv_kernel<<<dim3(KVCHUNKS, NH, 4), 256, 0, stream>>>(kb, vb, KVp);
    prep_kernel<<<288, 256, 0, stream>>>(KVp, KV, KS, proj_w, wfrag);
    attn_kernel<<<dim3(128, NH, 4), 64, 0, stream>>>(qb, KV, KS, (unsigned int*)aof);
    conv_kernel<<<1024, 256, 0, stream>>>(aof, wfrag, proj_b, out);
}